// Round 1
// baseline (1366.058 us; speedup 1.0000x reference)
//
#include <hip/hip_runtime.h>
#include <hip/hip_bf16.h>
#include <cstddef>
#include <cstdint>

#define NNODES 50000
#define NEDGES 1600000
#define DIM 256
#define HID 128
#define FCU 1024
#define NCLS 16

// ---------------- graph preprocessing ----------------

__global__ void count_kernel(const int* __restrict__ ei, int* __restrict__ degS,
                             int* __restrict__ cnt) {
    int e = blockIdx.x * blockDim.x + threadIdx.x;
    if (e < NEDGES) {
        atomicAdd(&degS[ei[e]], 1);            // out-degree by src (matches reference deg)
        atomicAdd(&cnt[ei[NEDGES + e]], 1);    // in-count by dst (for CSR)
    }
}

__global__ void norm_kernel(const int* __restrict__ degS, float* __restrict__ nrm) {
    int i = blockIdx.x * blockDim.x + threadIdx.x;
    if (i < NNODES) nrm[i] = rsqrtf((float)(degS[i] + 1));  // +1 self loop
}

// single-block exclusive scan over dst counts -> rowptr, cursor
__global__ void scan_kernel(const int* __restrict__ cnt, int* __restrict__ rowptr,
                            int* __restrict__ cursor) {
    __shared__ int s[1024];
    __shared__ int carry;
    int tid = threadIdx.x;
    if (tid == 0) carry = 0;
    __syncthreads();
    for (int start = 0; start < NNODES; start += 1024) {
        int i = start + tid;
        int v = (i < NNODES) ? cnt[i] : 0;
        s[tid] = v;
        __syncthreads();
        for (int off = 1; off < 1024; off <<= 1) {
            int t = (tid >= off) ? s[tid - off] : 0;
            __syncthreads();
            s[tid] += t;
            __syncthreads();
        }
        int incl = s[tid];
        int c = carry;
        int excl = c + incl - v;
        if (i < NNODES) { rowptr[i] = excl; cursor[i] = excl; }
        __syncthreads();
        if (tid == 1023) carry = c + incl;
        __syncthreads();
    }
    if (tid == 0) rowptr[NNODES] = carry;
}

__global__ void fill_kernel(const int* __restrict__ ei, int* __restrict__ cursor,
                            int* __restrict__ csr) {
    int e = blockIdx.x * blockDim.x + threadIdx.x;
    if (e < NEDGES) {
        int src = ei[e], dst = ei[NEDGES + e];
        int p = atomicAdd(&cursor[dst], 1);
        csr[p] = src;
    }
}

// ---------------- aggregation: agg[i] = nrm[i]*(sum_e nrm[s]*hw[s] + nrm[i]*hw[i]) + b ----------------

template<bool RELU>
__global__ __launch_bounds__(128) void agg_kernel(
    const float* __restrict__ hw, const float* __restrict__ nrm,
    const int* __restrict__ rowptr, const int* __restrict__ csr,
    const float* __restrict__ bias, float* __restrict__ out)
{
    int i = blockIdx.x;
    int f = threadIdx.x;
    float ni = nrm[i];
    float acc = ni * hw[(size_t)i * HID + f];
    int e0 = rowptr[i], e1 = rowptr[i + 1];
    for (int e = e0; e < e1; ++e) {
        int s = csr[e];
        acc += nrm[s] * hw[(size_t)s * HID + f];
    }
    float v = fmaf(ni, acc, bias[f]);
    if (RELU) v = fmaxf(v, 0.f);
    out[(size_t)i * HID + f] = v;
}

// ---------------- fp32 GEMM: out[M,128] = A[M,K] @ W[K,128] (+ per-node bias & relu) ----------------

template<int K, int MODE>  // MODE 0: plain, 1: per-node bias + relu
__global__ __launch_bounds__(256) void gemm_h(
    const float* __restrict__ A, const float* __restrict__ W,
    const float* __restrict__ bias, float* __restrict__ out, int M)
{
    const int BM = 64, BN = 128, BK = 16;
    __shared__ float As[BK][BM];
    __shared__ float Ws[BK][BN];
    int tid = threadIdx.x;
    int ty = tid >> 5;        // 0..7  -> 8 rows each
    int tx = tid & 31;        // 0..31 -> 4 cols each
    int m0 = ty * 8, n0 = tx * 4;
    int blockRow = blockIdx.x * BM;
    float acc[8][4] = {};

    for (int kk = 0; kk < K; kk += BK) {
        {   // stage A 64x16 (float4 per thread)
            int m = tid & 63, kq = (tid >> 6) << 2;
            int row = blockRow + m; if (row >= M) row = M - 1;
            const float4 v = *reinterpret_cast<const float4*>(A + (size_t)row * K + kk + kq);
            As[kq + 0][m] = v.x; As[kq + 1][m] = v.y; As[kq + 2][m] = v.z; As[kq + 3][m] = v.w;
        }
        {   // stage W 16x128 (2x float4 per thread)
            int k = tid >> 4, n = (tid & 15) * 8;
            const float* wp = W + (size_t)(kk + k) * BN + n;
            float4 v0 = *reinterpret_cast<const float4*>(wp);
            float4 v1 = *reinterpret_cast<const float4*>(wp + 4);
            *reinterpret_cast<float4*>(&Ws[k][n]) = v0;
            *reinterpret_cast<float4*>(&Ws[k][n + 4]) = v1;
        }
        __syncthreads();
#pragma unroll
        for (int k = 0; k < BK; ++k) {
            float a[8], b[4];
            *reinterpret_cast<float4*>(a)     = *reinterpret_cast<const float4*>(&As[k][m0]);
            *reinterpret_cast<float4*>(a + 4) = *reinterpret_cast<const float4*>(&As[k][m0 + 4]);
            *reinterpret_cast<float4*>(b)     = *reinterpret_cast<const float4*>(&Ws[k][n0]);
#pragma unroll
            for (int i = 0; i < 8; ++i) {
#pragma unroll
                for (int j = 0; j < 4; ++j) acc[i][j] = fmaf(a[i], b[j], acc[i][j]);
            }
        }
        __syncthreads();
    }
#pragma unroll
    for (int i = 0; i < 8; ++i) {
        int row = blockRow + m0 + i;
        if (row < M) {
            float4 v; v.x = acc[i][0]; v.y = acc[i][1]; v.z = acc[i][2]; v.w = acc[i][3];
            if (MODE == 1) {
                const float4 bb = *reinterpret_cast<const float4*>(bias + (size_t)row * BN + n0);
                v.x = fmaxf(v.x + bb.x, 0.f); v.y = fmaxf(v.y + bb.y, 0.f);
                v.z = fmaxf(v.z + bb.z, 0.f); v.w = fmaxf(v.w + bb.w, 0.f);
            }
            *reinterpret_cast<float4*>(out + (size_t)row * BN + n0) = v;
        }
    }
}

// ---------------- fused head: out = relu((h1+h2)@W0 + b0) @ W1 + b1 ----------------

__global__ __launch_bounds__(256) void fc_fused_kernel(
    const float* __restrict__ h1, const float* __restrict__ h2,
    const float* __restrict__ W0, const float* __restrict__ b0,
    const float* __restrict__ W1, const float* __restrict__ b1c,
    float* __restrict__ out, int M)
{
    const int BM = 64;
    __shared__ float hs[BM][HID + 1];   // 64 x 129
    __shared__ float Ws[16][128];       // fc0 W k-slice for current col chunk
    __shared__ float W1s[128][NCLS];    // fc1 rows for current col chunk
    int tid = threadIdx.x;
    int ty = tid >> 4;      // 0..15 -> 4 rows each
    int tx = tid & 15;      // 0..15 -> 8 chunk-cols each
    int m0 = ty * 4, n0 = tx * 8;
    int blockRow = blockIdx.x * BM;

    for (int idx = tid; idx < BM * HID; idx += 256) {
        int m = idx >> 7, k = idx & 127;
        int row = blockRow + m;
        float v = 0.f;
        if (row < M) v = h1[(size_t)row * HID + k] + h2[(size_t)row * HID + k];
        hs[m][k] = v;
    }

    float p[4][NCLS] = {};
    for (int oc = 0; oc < FCU; oc += 128) {
        {   // stage fc1 chunk rows
            int r = tid >> 1, half = (tid & 1) * 8;
            const float4 v0 = *reinterpret_cast<const float4*>(W1 + (size_t)(oc + r) * NCLS + half);
            const float4 v1 = *reinterpret_cast<const float4*>(W1 + (size_t)(oc + r) * NCLS + half + 4);
            *reinterpret_cast<float4*>(&W1s[r][half]) = v0;
            *reinterpret_cast<float4*>(&W1s[r][half + 4]) = v1;
        }
        float tacc[4][8] = {};
        for (int kk = 0; kk < HID; kk += 16) {
            {
                int k = tid >> 4, n = (tid & 15) * 8;
                const float* wp = W0 + (size_t)(kk + k) * FCU + oc + n;
                float4 v0 = *reinterpret_cast<const float4*>(wp);
                float4 v1 = *reinterpret_cast<const float4*>(wp + 4);
                *reinterpret_cast<float4*>(&Ws[k][n]) = v0;
                *reinterpret_cast<float4*>(&Ws[k][n + 4]) = v1;
            }
            __syncthreads();
#pragma unroll
            for (int k = 0; k < 16; ++k) {
                float a[4], b[8];
#pragma unroll
                for (int i = 0; i < 4; ++i) a[i] = hs[m0 + i][kk + k];
                *reinterpret_cast<float4*>(b)     = *reinterpret_cast<const float4*>(&Ws[k][n0]);
                *reinterpret_cast<float4*>(b + 4) = *reinterpret_cast<const float4*>(&Ws[k][n0 + 4]);
#pragma unroll
                for (int i = 0; i < 4; ++i)
#pragma unroll
                    for (int j = 0; j < 8; ++j) tacc[i][j] = fmaf(a[i], b[j], tacc[i][j]);
            }
            __syncthreads();
        }
        // relu + accumulate into fc1 partials
#pragma unroll
        for (int j = 0; j < 8; ++j) {
            float bj = b0[oc + n0 + j];
            float w1row[NCLS];
#pragma unroll
            for (int c = 0; c < NCLS; c += 4)
                *reinterpret_cast<float4*>(w1row + c) = *reinterpret_cast<const float4*>(&W1s[n0 + j][c]);
#pragma unroll
            for (int i = 0; i < 4; ++i) {
                float tv = fmaxf(tacc[i][j] + bj, 0.f);
#pragma unroll
                for (int c = 0; c < NCLS; ++c) p[i][c] = fmaf(tv, w1row[c], p[i][c]);
            }
        }
        __syncthreads();   // protect W1s/Ws before next chunk overwrites
    }

    // reduce partials across the 16 tx lanes (they partition the 1024 fc0 units)
#pragma unroll
    for (int i = 0; i < 4; ++i)
#pragma unroll
        for (int c = 0; c < NCLS; ++c) {
            float v = p[i][c];
            v += __shfl_xor(v, 1);
            v += __shfl_xor(v, 2);
            v += __shfl_xor(v, 4);
            v += __shfl_xor(v, 8);
            p[i][c] = v;
        }
    if (tx == 0) {
#pragma unroll
        for (int i = 0; i < 4; ++i) {
            int row = blockRow + m0 + i;
            if (row < M) {
#pragma unroll
                for (int c = 0; c < NCLS; c += 4) {
                    float4 v;
                    v.x = p[i][c]     + b1c[c];
                    v.y = p[i][c + 1] + b1c[c + 1];
                    v.z = p[i][c + 2] + b1c[c + 2];
                    v.w = p[i][c + 3] + b1c[c + 3];
                    *reinterpret_cast<float4*>(out + (size_t)row * NCLS + c) = v;
                }
            }
        }
    }
}

// ---------------- launch ----------------

extern "C" void kernel_launch(void* const* d_in, const int* in_sizes, int n_in,
                              void* d_out, int out_size, void* d_ws, size_t ws_size,
                              hipStream_t stream)
{
    const float* x     = (const float*)d_in[0];
    const int*   ei    = (const int*)d_in[1];
    const float* gcn0W = (const float*)d_in[2];
    const float* gcn0b = (const float*)d_in[3];
    const float* gcn1W = (const float*)d_in[4];
    const float* gcn1b = (const float*)d_in[5];
    const float* gcn2W = (const float*)d_in[6];
    const float* gcn2b = (const float*)d_in[7];
    const float* w1    = (const float*)d_in[8];
    const float* b1    = (const float*)d_in[9];
    const float* fc0W  = (const float*)d_in[10];
    const float* fc0b  = (const float*)d_in[11];
    const float* fc1W  = (const float*)d_in[12];
    const float* fc1b  = (const float*)d_in[13];
    float* out = (float*)d_out;

    char* ws = (char*)d_ws;
    size_t off = 0;
    auto alloc = [&](size_t bytes) -> void* {
        void* p = ws + off;
        off = (off + bytes + 255) & ~(size_t)255;
        return p;
    };
    int* degS    = (int*)alloc((size_t)2 * NNODES * 4);    // degS + cnt contiguous (one memset)
    int* cnt     = degS + NNODES;
    int* rowptr  = (int*)alloc((size_t)(NNODES + 1) * 4);
    int* cursor  = (int*)alloc((size_t)NNODES * 4);
    int* csr     = (int*)alloc((size_t)NEDGES * 4);
    float* nrm   = (float*)alloc((size_t)NNODES * 4);
    float* bufA  = (float*)alloc((size_t)NNODES * HID * 4);
    float* bufB  = (float*)alloc((size_t)NNODES * HID * 4);
    float* bufH1 = (float*)alloc((size_t)NNODES * HID * 4);

    hipMemsetAsync(degS, 0, (size_t)2 * NNODES * 4, stream);
    count_kernel<<<(NEDGES + 255) / 256, 256, 0, stream>>>(ei, degS, cnt);
    norm_kernel<<<(NNODES + 255) / 256, 256, 0, stream>>>(degS, nrm);
    scan_kernel<<<1, 1024, 0, stream>>>(cnt, rowptr, cursor);
    fill_kernel<<<(NEDGES + 255) / 256, 256, 0, stream>>>(ei, cursor, csr);

    const int GB = (NNODES + 63) / 64;
    // gcn0: xW0 -> agg+bias+relu -> h1
    gemm_h<DIM, 0><<<GB, 256, 0, stream>>>(x, gcn0W, nullptr, bufA, NNODES);
    agg_kernel<true><<<NNODES, 128, 0, stream>>>(bufA, nrm, rowptr, csr, gcn0b, bufH1);
    // h11 = relu(h1@w1 + b1)
    gemm_h<HID, 1><<<GB, 256, 0, stream>>>(bufH1, w1, b1, bufB, NNODES);
    // gcn1: h11@W1 -> agg+bias (no relu) -> h2a
    gemm_h<HID, 0><<<GB, 256, 0, stream>>>(bufB, gcn1W, nullptr, bufA, NNODES);
    agg_kernel<false><<<NNODES, 128, 0, stream>>>(bufA, nrm, rowptr, csr, gcn1b, bufB);
    // gcn2: h2a@W2 -> agg+bias+relu -> h2
    gemm_h<HID, 0><<<GB, 256, 0, stream>>>(bufB, gcn2W, nullptr, bufA, NNODES);
    agg_kernel<true><<<NNODES, 128, 0, stream>>>(bufA, nrm, rowptr, csr, gcn2b, bufB);
    // head: out = relu((h1+h2)@fc0W + fc0b) @ fc1W + fc1b
    fc_fused_kernel<<<GB, 256, 0, stream>>>(bufH1, bufB, fc0W, fc0b, fc1W, fc1b, out, NNODES);
}

// Round 2
// 927.247 us; speedup vs baseline: 1.4732x; 1.4732x over previous
//
#include <hip/hip_runtime.h>
#include <hip/hip_bf16.h>
#include <cstddef>
#include <cstdint>

#define NNODES 50000
#define NEDGES 1600000
#define DIM 256
#define HID 128
#define FCU 1024
#define NCLS 16

typedef short s16x8 __attribute__((ext_vector_type(8)));
typedef float f32x4 __attribute__((ext_vector_type(4)));
#define MFMA16 __builtin_amdgcn_mfma_f32_16x16x32_bf16

typedef unsigned short u16;
typedef unsigned int u32;

__device__ inline u16 f2bf(float f) {
    u32 u = __float_as_uint(f);
    return (u16)((u + 0x7FFF + ((u >> 16) & 1)) >> 16);
}
__device__ inline float bf2f(u16 h) { return __uint_as_float(((u32)h) << 16); }
__device__ inline void split2(float v, u16& h, u16& l) {
    h = f2bf(v);
    l = f2bf(v - bf2f(h));
}

// ---------------- graph preprocessing ----------------

__global__ void count_kernel(const int* __restrict__ ei, int* __restrict__ degS,
                             int* __restrict__ cnt) {
    int e = blockIdx.x * blockDim.x + threadIdx.x;
    if (e < NEDGES) {
        atomicAdd(&degS[ei[e]], 1);
        atomicAdd(&cnt[ei[NEDGES + e]], 1);
    }
}

__global__ void norm_kernel(const int* __restrict__ degS, float* __restrict__ nrm) {
    int i = blockIdx.x * blockDim.x + threadIdx.x;
    if (i < NNODES) nrm[i] = rsqrtf((float)(degS[i] + 1));
}

// 3-phase scan: per-block exclusive scan + block sums
__global__ __launch_bounds__(1024) void scan_a(const int* __restrict__ cnt,
                                               int* __restrict__ rowptr, int* __restrict__ bsum) {
    __shared__ int s[1024];
    int b = blockIdx.x, t = threadIdx.x, i = b * 1024 + t;
    int v = (i < NNODES) ? cnt[i] : 0;
    s[t] = v;
    __syncthreads();
    for (int off = 1; off < 1024; off <<= 1) {
        int x = (t >= off) ? s[t - off] : 0;
        __syncthreads();
        s[t] += x;
        __syncthreads();
    }
    if (i < NNODES) rowptr[i] = s[t] - v;           // block-local exclusive
    if (t == 1023) bsum[b] = s[1023];
}
__global__ void scan_b(int* __restrict__ bsum, int nb) {
    if (threadIdx.x == 0 && blockIdx.x == 0) {
        int a = 0;
        for (int j = 0; j < nb; ++j) { int t = bsum[j]; bsum[j] = a; a += t; }
    }
}
__global__ __launch_bounds__(1024) void scan_c(int* __restrict__ rowptr, int* __restrict__ cursor,
                                               const int* __restrict__ bsum) {
    int b = blockIdx.x, t = threadIdx.x, i = b * 1024 + t;
    if (i < NNODES) {
        int v = rowptr[i] + bsum[b];
        rowptr[i] = v;
        cursor[i] = v;
    }
    if (i == 0) rowptr[NNODES] = NEDGES;
}

__global__ void fill_kernel(const int* __restrict__ ei, int* __restrict__ cursor,
                            int* __restrict__ csr) {
    int e = blockIdx.x * blockDim.x + threadIdx.x;
    if (e < NEDGES) {
        int src = ei[e], dst = ei[NEDGES + e];
        int p = atomicAdd(&cursor[dst], 1);
        csr[p] = src;
    }
}

// ---------------- conversions ----------------

// x fp32 [N,256] -> hi/lo bf16 planes
__global__ __launch_bounds__(256) void conv_x(const float* __restrict__ x,
                                              u16* __restrict__ xh, u16* __restrict__ xl) {
    int i = blockIdx.x * blockDim.x + threadIdx.x;    // one float4 per thread
    const float4 v = *reinterpret_cast<const float4*>(x + (size_t)i * 4);
    u16 h0, l0, h1, l1, h2, l2, h3, l3;
    split2(v.x, h0, l0); split2(v.y, h1, l1); split2(v.z, h2, l2); split2(v.w, h3, l3);
    ushort4 hv = make_ushort4(h0, h1, h2, h3), lv = make_ushort4(l0, l1, l2, l3);
    *reinterpret_cast<ushort4*>(xh + (size_t)i * 4) = hv;
    *reinterpret_cast<ushort4*>(xl + (size_t)i * 4) = lv;
}

// W fp32 [K,N] -> WT hi/lo bf16 [N,K]
__global__ __launch_bounds__(256) void conv_wT(const float* __restrict__ W, int K, int N,
                                               u16* __restrict__ outH, u16* __restrict__ outL) {
    int o = blockIdx.x * blockDim.x + threadIdx.x;
    if (o < K * N) {
        int n = o / K, k = o - n * K;
        u16 h, l;
        split2(W[(size_t)k * N + n], h, l);
        outH[o] = h; outL[o] = l;
    }
}

// ---------------- aggregation (reads fp32, writes hi/lo planes) ----------------
// VAR 0: relu   VAR 1: plain   VAR 2: relu + add h1 (residual)

template<int VAR>
__global__ __launch_bounds__(128) void agg_split(
    const float* __restrict__ hw, const float* __restrict__ nrm,
    const int* __restrict__ rowptr, const int* __restrict__ csr,
    const float* __restrict__ bias,
    const u16* __restrict__ h1H, const u16* __restrict__ h1L,
    u16* __restrict__ outH, u16* __restrict__ outL)
{
    int i = blockIdx.x;
    int f = threadIdx.x;
    float ni = nrm[i];
    float acc = ni * hw[(size_t)i * HID + f];
    int e0 = rowptr[i], e1 = rowptr[i + 1];
    for (int e = e0; e < e1; ++e) {
        int s = csr[e];
        acc = fmaf(nrm[s], hw[(size_t)s * HID + f], acc);
    }
    float v = fmaf(ni, acc, bias[f]);
    if (VAR != 1) v = fmaxf(v, 0.f);
    if (VAR == 2) v += bf2f(h1H[(size_t)i * HID + f]) + bf2f(h1L[(size_t)i * HID + f]);
    u16 h, l;
    split2(v, h, l);
    outH[(size_t)i * HID + f] = h;
    outL[(size_t)i * HID + f] = l;
}

// ---------------- split-bf16 MFMA GEMM: [M,K] @ [K,128] ----------------
// A as hi/lo bf16 planes [M,K]; B as transposed hi/lo planes [128,K].
// MODE 0: out fp32 [M,128].  MODE 1: per-node bias (b1) + relu, out hi/lo planes.

template<int K, int MODE>
__global__ __launch_bounds__(256) void gemm_split(
    const u16* __restrict__ Ah, const u16* __restrict__ Al,
    const u16* __restrict__ BTh, const u16* __restrict__ BTl,
    const float* __restrict__ pnb,
    float* __restrict__ outF, u16* __restrict__ outH, u16* __restrict__ outL, int M)
{
    const int PK = 40;   // 32 + 8 pad (2-way bank conflicts only)
    __shared__ __align__(16) u16 AsH[64 * PK], AsL[64 * PK];
    __shared__ __align__(16) u16 BsH[128 * PK], BsL[128 * PK];
    int tid = threadIdx.x, lane = tid & 63, w = tid >> 6;
    int wr = w >> 1, wc = w & 1;          // wave tile: 32 rows x 64 cols
    int l15 = lane & 15, l4 = lane >> 4;
    int blockRow = blockIdx.x * 64;
    f32x4 acc[2][4] = {};

    for (int kk = 0; kk < K; kk += 32) {
        {   // stage A 64x32 (both planes), 1 chunk of 8 per thread
            int row = tid >> 2, kc = (tid & 3) * 8;
            int gr = blockRow + row; if (gr >= M) gr = M - 1;
            *(s16x8*)&AsH[row * PK + kc] = *(const s16x8*)&Ah[(size_t)gr * K + kk + kc];
            *(s16x8*)&AsL[row * PK + kc] = *(const s16x8*)&Al[(size_t)gr * K + kk + kc];
        }
#pragma unroll
        for (int i2 = 0; i2 < 2; ++i2) {   // stage B 128x32, 2 chunks per thread
            int idx = tid + i2 * 256;
            int n = idx >> 2, kc = (idx & 3) * 8;
            *(s16x8*)&BsH[n * PK + kc] = *(const s16x8*)&BTh[(size_t)n * K + kk + kc];
            *(s16x8*)&BsL[n * PK + kc] = *(const s16x8*)&BTl[(size_t)n * K + kk + kc];
        }
        __syncthreads();
        s16x8 ah[2], al[2], bh[4], bl[4];
#pragma unroll
        for (int mi = 0; mi < 2; ++mi) {
            ah[mi] = *(const s16x8*)&AsH[(wr * 32 + mi * 16 + l15) * PK + 8 * l4];
            al[mi] = *(const s16x8*)&AsL[(wr * 32 + mi * 16 + l15) * PK + 8 * l4];
        }
#pragma unroll
        for (int ni = 0; ni < 4; ++ni) {
            bh[ni] = *(const s16x8*)&BsH[(wc * 64 + ni * 16 + l15) * PK + 8 * l4];
            bl[ni] = *(const s16x8*)&BsL[(wc * 64 + ni * 16 + l15) * PK + 8 * l4];
        }
#pragma unroll
        for (int mi = 0; mi < 2; ++mi)
#pragma unroll
            for (int ni = 0; ni < 4; ++ni) {
                acc[mi][ni] = MFMA16(ah[mi], bh[ni], acc[mi][ni], 0, 0, 0);
                acc[mi][ni] = MFMA16(ah[mi], bl[ni], acc[mi][ni], 0, 0, 0);
                acc[mi][ni] = MFMA16(al[mi], bh[ni], acc[mi][ni], 0, 0, 0);
            }
        __syncthreads();
    }
#pragma unroll
    for (int mi = 0; mi < 2; ++mi)
#pragma unroll
        for (int ni = 0; ni < 4; ++ni) {
            int c = wc * 64 + ni * 16 + l15;
#pragma unroll
            for (int j = 0; j < 4; ++j) {
                int r = blockRow + wr * 32 + mi * 16 + l4 * 4 + j;
                if (r < M) {
                    if (MODE == 0) {
                        outF[(size_t)r * 128 + c] = acc[mi][ni][j];
                    } else {
                        float v = fmaxf(acc[mi][ni][j] + pnb[(size_t)r * 128 + c], 0.f);
                        u16 h, l;
                        split2(v, h, l);
                        outH[(size_t)r * 128 + c] = h;
                        outL[(size_t)r * 128 + c] = l;
                    }
                }
            }
        }
}

// ---------------- fused fc head: relu(h@fc0W+b0) chunk -> fc1 partial (atomic) ----------------

__global__ void init_out(const float* __restrict__ fc1b, float* __restrict__ out) {
    int i = blockIdx.x * blockDim.x + threadIdx.x;
    if (i < NNODES * NCLS) out[i] = fc1b[i & 15];
}

__global__ __launch_bounds__(256) void fc_kernel(
    const u16* __restrict__ Ah, const u16* __restrict__ Al,
    const u16* __restrict__ BTh, const u16* __restrict__ BTl,   // fc0T [1024,128]
    const float* __restrict__ fc0b,
    const u16* __restrict__ W1Th, const u16* __restrict__ W1Tl, // fc1T [16,1024]
    float* __restrict__ out, int M)
{
    const int PK = 40;
    __shared__ __align__(16) u16 lds[21760];
    u16* AsH = lds;            // 64*40 = 2560
    u16* AsL = lds + 2560;
    u16* BsH = lds + 5120;     // 128*40 = 5120
    u16* BsL = lds + 10240;
    int tid = threadIdx.x, lane = tid & 63, w = tid >> 6;
    int wr = w >> 1, wc = w & 1;
    int l15 = lane & 15, l4 = lane >> 4;
    int blockRow = blockIdx.x * 64;
    int co = blockIdx.y * 128;
    f32x4 acc[2][4] = {};

    for (int kk = 0; kk < HID; kk += 32) {
        {
            int row = tid >> 2, kc = (tid & 3) * 8;
            int gr = blockRow + row; if (gr >= M) gr = M - 1;
            *(s16x8*)&AsH[row * PK + kc] = *(const s16x8*)&Ah[(size_t)gr * HID + kk + kc];
            *(s16x8*)&AsL[row * PK + kc] = *(const s16x8*)&Al[(size_t)gr * HID + kk + kc];
        }
#pragma unroll
        for (int i2 = 0; i2 < 2; ++i2) {
            int idx = tid + i2 * 256;
            int n = idx >> 2, kc = (idx & 3) * 8;
            *(s16x8*)&BsH[n * PK + kc] = *(const s16x8*)&BTh[(size_t)(co + n) * HID + kk + kc];
            *(s16x8*)&BsL[n * PK + kc] = *(const s16x8*)&BTl[(size_t)(co + n) * HID + kk + kc];
        }
        __syncthreads();
        s16x8 ah[2], al[2], bh[4], bl[4];
#pragma unroll
        for (int mi = 0; mi < 2; ++mi) {
            ah[mi] = *(const s16x8*)&AsH[(wr * 32 + mi * 16 + l15) * PK + 8 * l4];
            al[mi] = *(const s16x8*)&AsL[(wr * 32 + mi * 16 + l15) * PK + 8 * l4];
        }
#pragma unroll
        for (int ni = 0; ni < 4; ++ni) {
            bh[ni] = *(const s16x8*)&BsH[(wc * 64 + ni * 16 + l15) * PK + 8 * l4];
            bl[ni] = *(const s16x8*)&BsL[(wc * 64 + ni * 16 + l15) * PK + 8 * l4];
        }
#pragma unroll
        for (int mi = 0; mi < 2; ++mi)
#pragma unroll
            for (int ni = 0; ni < 4; ++ni) {
                acc[mi][ni] = MFMA16(ah[mi], bh[ni], acc[mi][ni], 0, 0, 0);
                acc[mi][ni] = MFMA16(ah[mi], bl[ni], acc[mi][ni], 0, 0, 0);
                acc[mi][ni] = MFMA16(al[mi], bh[ni], acc[mi][ni], 0, 0, 0);
            }
        __syncthreads();
    }

    // overlay LDS: relu'd fc0 values as hi/lo bf16 + fc1 weight chunk
    u16* vH = lds;              // 64*136 = 8704
    u16* vL = lds + 8704;
    u16* W1sH = lds + 17408;    // 16*136 = 2176
    u16* W1sL = lds + 19584;
    {
        int cls = tid >> 4, kc = (tid & 15) * 8;
        *(s16x8*)&W1sH[cls * 136 + kc] = *(const s16x8*)&W1Th[(size_t)cls * FCU + co + kc];
        *(s16x8*)&W1sL[cls * 136 + kc] = *(const s16x8*)&W1Tl[(size_t)cls * FCU + co + kc];
    }
#pragma unroll
    for (int mi = 0; mi < 2; ++mi)
#pragma unroll
        for (int ni = 0; ni < 4; ++ni) {
            int unit = wc * 64 + ni * 16 + l15;
            float b0v = fc0b[co + unit];
#pragma unroll
            for (int j = 0; j < 4; ++j) {
                int rl = wr * 32 + mi * 16 + l4 * 4 + j;
                float v = fmaxf(acc[mi][ni][j] + b0v, 0.f);
                u16 h, l;
                split2(v, h, l);
                vH[rl * 136 + unit] = h;
                vL[rl * 136 + unit] = l;
            }
        }
    __syncthreads();

    // fc1: each wave does 16 rows x 16 classes over this block's 128 units
    f32x4 acc2 = {0.f, 0.f, 0.f, 0.f};
#pragma unroll
    for (int ks = 0; ks < 4; ++ks) {
        s16x8 a2h = *(const s16x8*)&vH[(w * 16 + l15) * 136 + ks * 32 + 8 * l4];
        s16x8 a2l = *(const s16x8*)&vL[(w * 16 + l15) * 136 + ks * 32 + 8 * l4];
        s16x8 b2h = *(const s16x8*)&W1sH[l15 * 136 + ks * 32 + 8 * l4];
        s16x8 b2l = *(const s16x8*)&W1sL[l15 * 136 + ks * 32 + 8 * l4];
        acc2 = MFMA16(a2h, b2h, acc2, 0, 0, 0);
        acc2 = MFMA16(a2h, b2l, acc2, 0, 0, 0);
        acc2 = MFMA16(a2l, b2h, acc2, 0, 0, 0);
    }
#pragma unroll
    for (int j = 0; j < 4; ++j) {
        int gr = blockRow + w * 16 + l4 * 4 + j;
        if (gr < M) atomicAdd(&out[(size_t)gr * NCLS + l15], acc2[j]);
    }
}

// ---------------- launch ----------------

extern "C" void kernel_launch(void* const* d_in, const int* in_sizes, int n_in,
                              void* d_out, int out_size, void* d_ws, size_t ws_size,
                              hipStream_t stream)
{
    const float* x     = (const float*)d_in[0];
    const int*   ei    = (const int*)d_in[1];
    const float* gcn0W = (const float*)d_in[2];
    const float* gcn0b = (const float*)d_in[3];
    const float* gcn1W = (const float*)d_in[4];
    const float* gcn1b = (const float*)d_in[5];
    const float* gcn2W = (const float*)d_in[6];
    const float* gcn2b = (const float*)d_in[7];
    const float* w1    = (const float*)d_in[8];
    const float* b1    = (const float*)d_in[9];
    const float* fc0W  = (const float*)d_in[10];
    const float* fc0b  = (const float*)d_in[11];
    const float* fc1W  = (const float*)d_in[12];
    const float* fc1b  = (const float*)d_in[13];
    float* out = (float*)d_out;

    char* ws = (char*)d_ws;
    size_t off = 0;
    auto alloc = [&](size_t bytes) -> void* {
        void* p = ws + off;
        off = (off + bytes + 255) & ~(size_t)255;
        return p;
    };
    int* degS   = (int*)alloc((size_t)2 * NNODES * 4);  // degS + cnt (one memset)
    int* cnt    = degS + NNODES;
    int* rowptr = (int*)alloc((size_t)(NNODES + 1) * 4);
    int* cursor = (int*)alloc((size_t)NNODES * 4);
    int* bsum   = (int*)alloc(64 * 4);
    int* csr    = (int*)alloc((size_t)NEDGES * 4);
    float* nrm  = (float*)alloc((size_t)NNODES * 4);
    // weight hi/lo transposed planes
    u16* W0Th = (u16*)alloc((size_t)DIM * HID * 2);  u16* W0Tl = (u16*)alloc((size_t)DIM * HID * 2);
    u16* w1Th = (u16*)alloc((size_t)HID * HID * 2);  u16* w1Tl = (u16*)alloc((size_t)HID * HID * 2);
    u16* W1Th = (u16*)alloc((size_t)HID * HID * 2);  u16* W1Tl = (u16*)alloc((size_t)HID * HID * 2);
    u16* W2Th = (u16*)alloc((size_t)HID * HID * 2);  u16* W2Tl = (u16*)alloc((size_t)HID * HID * 2);
    u16* F0Th = (u16*)alloc((size_t)HID * FCU * 2);  u16* F0Tl = (u16*)alloc((size_t)HID * FCU * 2);
    u16* F1Th = (u16*)alloc((size_t)FCU * NCLS * 2); u16* F1Tl = (u16*)alloc((size_t)FCU * NCLS * 2);
    float* bufG = (float*)alloc((size_t)NNODES * HID * 4);          // fp32 gemm outs for agg
    u16* R1 = (u16*)alloc((size_t)2 * NNODES * DIM * 2);            // 51.2MB: x planes, then h buffers
    // region reuse: x hi/lo live only until gemm0
    u16* xh = R1, *xl = R1 + (size_t)NNODES * DIM;
    u16* h1H = R1,                          *h1L = R1 + (size_t)NNODES * HID;       // after gemm0
    u16* B3H = R1 + (size_t)2 * NNODES * HID, *B3L = R1 + (size_t)3 * NNODES * HID; // h11/h2a/h

    const int M = NNODES;
    hipMemsetAsync(degS, 0, (size_t)2 * NNODES * 4, stream);

    // preprocessing
    count_kernel<<<(NEDGES + 255) / 256, 256, 0, stream>>>(ei, degS, cnt);
    norm_kernel<<<(NNODES + 255) / 256, 256, 0, stream>>>(degS, nrm);
    const int NB = (NNODES + 1023) / 1024;
    scan_a<<<NB, 1024, 0, stream>>>(cnt, rowptr, bsum);
    scan_b<<<1, 64, 0, stream>>>(bsum, NB);
    scan_c<<<NB, 1024, 0, stream>>>(rowptr, cursor, bsum);
    fill_kernel<<<(NEDGES + 255) / 256, 256, 0, stream>>>(ei, cursor, csr);

    // conversions
    conv_x<<<(NNODES * DIM / 4 + 255) / 256, 256, 0, stream>>>(x, xh, xl);
    conv_wT<<<(DIM * HID + 255) / 256, 256, 0, stream>>>(gcn0W, DIM, HID, W0Th, W0Tl);
    conv_wT<<<(HID * HID + 255) / 256, 256, 0, stream>>>(w1,    HID, HID, w1Th, w1Tl);
    conv_wT<<<(HID * HID + 255) / 256, 256, 0, stream>>>(gcn1W, HID, HID, W1Th, W1Tl);
    conv_wT<<<(HID * HID + 255) / 256, 256, 0, stream>>>(gcn2W, HID, HID, W2Th, W2Tl);
    conv_wT<<<(HID * FCU + 255) / 256, 256, 0, stream>>>(fc0W,  HID, FCU, F0Th, F0Tl);
    conv_wT<<<(FCU * NCLS + 255) / 256, 256, 0, stream>>>(fc1W, FCU, NCLS, F1Th, F1Tl);

    const int GB = (M + 63) / 64;
    // gcn0
    gemm_split<DIM, 0><<<GB, 256, 0, stream>>>(xh, xl, W0Th, W0Tl, nullptr, bufG, nullptr, nullptr, M);
    agg_split<0><<<NNODES, 128, 0, stream>>>(bufG, nrm, rowptr, csr, gcn0b, nullptr, nullptr, h1H, h1L);
    // h11 = relu(h1@w1 + b1)
    gemm_split<HID, 1><<<GB, 256, 0, stream>>>(h1H, h1L, w1Th, w1Tl, b1, nullptr, B3H, B3L, M);
    // gcn1 (no relu)
    gemm_split<HID, 0><<<GB, 256, 0, stream>>>(B3H, B3L, W1Th, W1Tl, nullptr, bufG, nullptr, nullptr, M);
    agg_split<1><<<NNODES, 128, 0, stream>>>(bufG, nrm, rowptr, csr, gcn1b, nullptr, nullptr, B3H, B3L);
    // gcn2 (relu) + residual h = h1 + h2
    gemm_split<HID, 0><<<GB, 256, 0, stream>>>(B3H, B3L, W2Th, W2Tl, nullptr, bufG, nullptr, nullptr, M);
    agg_split<2><<<NNODES, 128, 0, stream>>>(bufG, nrm, rowptr, csr, gcn2b, h1H, h1L, B3H, B3L);
    // head
    init_out<<<(NNODES * NCLS + 255) / 256, 256, 0, stream>>>(fc1b, out);
    fc_kernel<<<dim3(GB, FCU / 128), 256, 0, stream>>>(B3H, B3L, F0Th, F0Tl, fc0b, F1Th, F1Tl, out, M);
}

// Round 3
// 764.868 us; speedup vs baseline: 1.7860x; 1.2123x over previous
//
#include <hip/hip_runtime.h>
#include <hip/hip_bf16.h>
#include <cstddef>
#include <cstdint>

#define NNODES 50000
#define NEDGES 1600000
#define DIM 256
#define HID 128
#define FCU 1024
#define NCLS 16

typedef short s16x8 __attribute__((ext_vector_type(8)));
typedef float f32x4 __attribute__((ext_vector_type(4)));
#define MFMA16 __builtin_amdgcn_mfma_f32_16x16x32_bf16

typedef unsigned short u16;
typedef unsigned int u32;

__device__ inline u16 f2bf(float f) {
    u32 u = __float_as_uint(f);
    return (u16)((u + 0x7FFF + ((u >> 16) & 1)) >> 16);
}
__device__ inline float bf2f(u16 h) { return __uint_as_float(((u32)h) << 16); }
__device__ inline void split2(float v, u16& h, u16& l) {
    h = f2bf(v);
    l = f2bf(v - bf2f(h));
}

// ---------------- graph preprocessing ----------------

__global__ void count_kernel(const int* __restrict__ ei, int* __restrict__ degS,
                             int* __restrict__ cnt) {
    int e = blockIdx.x * blockDim.x + threadIdx.x;
    if (e < NEDGES) {
        atomicAdd(&degS[ei[e]], 1);
        atomicAdd(&cnt[ei[NEDGES + e]], 1);
    }
}

__global__ void norm_kernel(const int* __restrict__ degS, float* __restrict__ nrm) {
    int i = blockIdx.x * blockDim.x + threadIdx.x;
    if (i < NNODES) nrm[i] = rsqrtf((float)(degS[i] + 1));
}

// 3-phase scan
__global__ __launch_bounds__(1024) void scan_a(const int* __restrict__ cnt,
                                               int* __restrict__ rowptr, int* __restrict__ bsum) {
    __shared__ int s[1024];
    int b = blockIdx.x, t = threadIdx.x, i = b * 1024 + t;
    int v = (i < NNODES) ? cnt[i] : 0;
    s[t] = v;
    __syncthreads();
    for (int off = 1; off < 1024; off <<= 1) {
        int x = (t >= off) ? s[t - off] : 0;
        __syncthreads();
        s[t] += x;
        __syncthreads();
    }
    if (i < NNODES) rowptr[i] = s[t] - v;
    if (t == 1023) bsum[b] = s[1023];
}
__global__ void scan_b(int* __restrict__ bsum, int nb) {
    if (threadIdx.x == 0 && blockIdx.x == 0) {
        int a = 0;
        for (int j = 0; j < nb; ++j) { int t = bsum[j]; bsum[j] = a; a += t; }
    }
}
__global__ __launch_bounds__(1024) void scan_c(int* __restrict__ rowptr, int* __restrict__ cursor,
                                               const int* __restrict__ bsum) {
    int b = blockIdx.x, t = threadIdx.x, i = b * 1024 + t;
    if (i < NNODES) {
        int v = rowptr[i] + bsum[b];
        rowptr[i] = v;
        cursor[i] = v;
    }
    if (i == 0) rowptr[NNODES] = NEDGES;
}

__global__ void fill_kernel(const int* __restrict__ ei, int* __restrict__ cursor,
                            int* __restrict__ csr) {
    int e = blockIdx.x * blockDim.x + threadIdx.x;
    if (e < NEDGES) {
        int src = ei[e], dst = ei[NEDGES + e];
        int p = atomicAdd(&cursor[dst], 1);
        csr[p] = src;
    }
}

// ---------------- conversions ----------------

__global__ __launch_bounds__(256) void conv_x(const float* __restrict__ x,
                                              u16* __restrict__ xh, u16* __restrict__ xl) {
    int i = blockIdx.x * blockDim.x + threadIdx.x;
    const float4 v = *reinterpret_cast<const float4*>(x + (size_t)i * 4);
    u16 h0, l0, h1, l1, h2, l2, h3, l3;
    split2(v.x, h0, l0); split2(v.y, h1, l1); split2(v.z, h2, l2); split2(v.w, h3, l3);
    ushort4 hv = make_ushort4(h0, h1, h2, h3), lv = make_ushort4(l0, l1, l2, l3);
    *reinterpret_cast<ushort4*>(xh + (size_t)i * 4) = hv;
    *reinterpret_cast<ushort4*>(xl + (size_t)i * 4) = lv;
}

__global__ __launch_bounds__(256) void conv_wT(const float* __restrict__ W, int K, int N,
                                               u16* __restrict__ outH, u16* __restrict__ outL) {
    int o = blockIdx.x * blockDim.x + threadIdx.x;
    if (o < K * N) {
        int n = o / K, k = o - n * K;
        u16 h, l;
        split2(W[(size_t)k * N + n], h, l);
        outH[o] = h; outL[o] = l;
    }
}

// ---------------- aggregation ----------------
// g rows are PRE-SCALED by nrm[src] in the GEMM epilogue.
// out[i] = nrm[i]*(g[i] + sum_{s in N(i)} g[s]) + bias   (+relu / +residual)
// One wave per node; lane owns features {2*lane, 2*lane+1}; 8-deep gather pipeline.
// VAR 0: relu   VAR 1: plain   VAR 2: relu + add h1 (residual)

template<int VAR>
__global__ __launch_bounds__(256) void agg_fast(
    const float* __restrict__ g, const float* __restrict__ nrm,
    const int* __restrict__ rowptr, const int* __restrict__ csr,
    const float* __restrict__ bias,
    const u16* __restrict__ h1H, const u16* __restrict__ h1L,
    u16* __restrict__ outH, u16* __restrict__ outL)
{
    int w = threadIdx.x >> 6, lane = threadIdx.x & 63;
    int i = blockIdx.x * 4 + w;
    if (i >= NNODES) return;
    const float2* gp = reinterpret_cast<const float2*>(g);
    size_t lrow = (size_t)i * 64 + lane;
    float2 acc = gp[lrow];                       // self term (pre-scaled)
    int e0 = rowptr[i], e1 = rowptr[i + 1];
    int e = e0;
    for (; e + 8 <= e1; e += 8) {
        int s[8];
#pragma unroll
        for (int q = 0; q < 8; ++q) s[q] = csr[e + q];
        float2 v[8];
#pragma unroll
        for (int q = 0; q < 8; ++q) v[q] = gp[(size_t)s[q] * 64 + lane];
#pragma unroll
        for (int q = 0; q < 8; ++q) { acc.x += v[q].x; acc.y += v[q].y; }
    }
    for (; e < e1; ++e) {
        int s = csr[e];
        float2 v = gp[(size_t)s * 64 + lane];
        acc.x += v.x; acc.y += v.y;
    }
    float ni = nrm[i];
    const float2 b = *reinterpret_cast<const float2*>(bias + lane * 2);
    float v0 = fmaf(ni, acc.x, b.x);
    float v1 = fmaf(ni, acc.y, b.y);
    if (VAR != 1) { v0 = fmaxf(v0, 0.f); v1 = fmaxf(v1, 0.f); }
    if (VAR == 2) {
        ushort2 rh = *reinterpret_cast<const ushort2*>(h1H + (size_t)i * HID + lane * 2);
        ushort2 rl = *reinterpret_cast<const ushort2*>(h1L + (size_t)i * HID + lane * 2);
        v0 += bf2f(rh.x) + bf2f(rl.x);
        v1 += bf2f(rh.y) + bf2f(rl.y);
    }
    u16 h0, l0, h1v, l1v;
    split2(v0, h0, l0);
    split2(v1, h1v, l1v);
    *reinterpret_cast<ushort2*>(outH + (size_t)i * HID + lane * 2) = make_ushort2(h0, h1v);
    *reinterpret_cast<ushort2*>(outL + (size_t)i * HID + lane * 2) = make_ushort2(l0, l1v);
}

// ---------------- split-bf16 MFMA GEMM: [M,K] @ [K,128] ----------------
// MODE 0: out fp32 [M,128] scaled by nrm[r] (feeds aggregation).
// MODE 1: per-node bias (b1) + relu, out hi/lo planes.

template<int K, int MODE>
__global__ __launch_bounds__(256) void gemm_split(
    const u16* __restrict__ Ah, const u16* __restrict__ Al,
    const u16* __restrict__ BTh, const u16* __restrict__ BTl,
    const float* __restrict__ pnb, const float* __restrict__ nrmv,
    float* __restrict__ outF, u16* __restrict__ outH, u16* __restrict__ outL, int M)
{
    const int PK = 40;
    __shared__ __align__(16) u16 AsH[64 * PK], AsL[64 * PK];
    __shared__ __align__(16) u16 BsH[128 * PK], BsL[128 * PK];
    int tid = threadIdx.x, lane = tid & 63, w = tid >> 6;
    int wr = w >> 1, wc = w & 1;
    int l15 = lane & 15, l4 = lane >> 4;
    int blockRow = blockIdx.x * 64;
    f32x4 acc[2][4] = {};

    for (int kk = 0; kk < K; kk += 32) {
        {
            int row = tid >> 2, kc = (tid & 3) * 8;
            int gr = blockRow + row; if (gr >= M) gr = M - 1;
            *(s16x8*)&AsH[row * PK + kc] = *(const s16x8*)&Ah[(size_t)gr * K + kk + kc];
            *(s16x8*)&AsL[row * PK + kc] = *(const s16x8*)&Al[(size_t)gr * K + kk + kc];
        }
#pragma unroll
        for (int i2 = 0; i2 < 2; ++i2) {
            int idx = tid + i2 * 256;
            int n = idx >> 2, kc = (idx & 3) * 8;
            *(s16x8*)&BsH[n * PK + kc] = *(const s16x8*)&BTh[(size_t)n * K + kk + kc];
            *(s16x8*)&BsL[n * PK + kc] = *(const s16x8*)&BTl[(size_t)n * K + kk + kc];
        }
        __syncthreads();
        s16x8 ah[2], al[2], bh[4], bl[4];
#pragma unroll
        for (int mi = 0; mi < 2; ++mi) {
            ah[mi] = *(const s16x8*)&AsH[(wr * 32 + mi * 16 + l15) * PK + 8 * l4];
            al[mi] = *(const s16x8*)&AsL[(wr * 32 + mi * 16 + l15) * PK + 8 * l4];
        }
#pragma unroll
        for (int ni = 0; ni < 4; ++ni) {
            bh[ni] = *(const s16x8*)&BsH[(wc * 64 + ni * 16 + l15) * PK + 8 * l4];
            bl[ni] = *(const s16x8*)&BsL[(wc * 64 + ni * 16 + l15) * PK + 8 * l4];
        }
#pragma unroll
        for (int mi = 0; mi < 2; ++mi)
#pragma unroll
            for (int ni = 0; ni < 4; ++ni) {
                acc[mi][ni] = MFMA16(ah[mi], bh[ni], acc[mi][ni], 0, 0, 0);
                acc[mi][ni] = MFMA16(ah[mi], bl[ni], acc[mi][ni], 0, 0, 0);
                acc[mi][ni] = MFMA16(al[mi], bh[ni], acc[mi][ni], 0, 0, 0);
            }
        __syncthreads();
    }
#pragma unroll
    for (int mi = 0; mi < 2; ++mi)
#pragma unroll
        for (int ni = 0; ni < 4; ++ni) {
            int c = wc * 64 + ni * 16 + l15;
#pragma unroll
            for (int j = 0; j < 4; ++j) {
                int r = blockRow + wr * 32 + mi * 16 + l4 * 4 + j;
                if (r < M) {
                    if (MODE == 0) {
                        outF[(size_t)r * 128 + c] = nrmv[r] * acc[mi][ni][j];
                    } else {
                        float v = fmaxf(acc[mi][ni][j] + pnb[(size_t)r * 128 + c], 0.f);
                        u16 h, l;
                        split2(v, h, l);
                        outH[(size_t)r * 128 + c] = h;
                        outL[(size_t)r * 128 + c] = l;
                    }
                }
            }
        }
}

// ---------------- fused fc head ----------------

__global__ void init_out(const float* __restrict__ fc1b, float* __restrict__ out) {
    int i = blockIdx.x * blockDim.x + threadIdx.x;
    if (i < NNODES * NCLS) out[i] = fc1b[i & 15];
}

__global__ __launch_bounds__(256) void fc_kernel(
    const u16* __restrict__ Ah, const u16* __restrict__ Al,
    const u16* __restrict__ BTh, const u16* __restrict__ BTl,
    const float* __restrict__ fc0b,
    const u16* __restrict__ W1Th, const u16* __restrict__ W1Tl,
    float* __restrict__ out, int M)
{
    const int PK = 40;
    __shared__ __align__(16) u16 lds[21760];
    u16* AsH = lds;
    u16* AsL = lds + 2560;
    u16* BsH = lds + 5120;
    u16* BsL = lds + 10240;
    int tid = threadIdx.x, lane = tid & 63, w = tid >> 6;
    int wr = w >> 1, wc = w & 1;
    int l15 = lane & 15, l4 = lane >> 4;
    int blockRow = blockIdx.x * 64;
    int co = blockIdx.y * 128;
    f32x4 acc[2][4] = {};

    for (int kk = 0; kk < HID; kk += 32) {
        {
            int row = tid >> 2, kc = (tid & 3) * 8;
            int gr = blockRow + row; if (gr >= M) gr = M - 1;
            *(s16x8*)&AsH[row * PK + kc] = *(const s16x8*)&Ah[(size_t)gr * HID + kk + kc];
            *(s16x8*)&AsL[row * PK + kc] = *(const s16x8*)&Al[(size_t)gr * HID + kk + kc];
        }
#pragma unroll
        for (int i2 = 0; i2 < 2; ++i2) {
            int idx = tid + i2 * 256;
            int n = idx >> 2, kc = (idx & 3) * 8;
            *(s16x8*)&BsH[n * PK + kc] = *(const s16x8*)&BTh[(size_t)(co + n) * HID + kk + kc];
            *(s16x8*)&BsL[n * PK + kc] = *(const s16x8*)&BTl[(size_t)(co + n) * HID + kk + kc];
        }
        __syncthreads();
        s16x8 ah[2], al[2], bh[4], bl[4];
#pragma unroll
        for (int mi = 0; mi < 2; ++mi) {
            ah[mi] = *(const s16x8*)&AsH[(wr * 32 + mi * 16 + l15) * PK + 8 * l4];
            al[mi] = *(const s16x8*)&AsL[(wr * 32 + mi * 16 + l15) * PK + 8 * l4];
        }
#pragma unroll
        for (int ni = 0; ni < 4; ++ni) {
            bh[ni] = *(const s16x8*)&BsH[(wc * 64 + ni * 16 + l15) * PK + 8 * l4];
            bl[ni] = *(const s16x8*)&BsL[(wc * 64 + ni * 16 + l15) * PK + 8 * l4];
        }
#pragma unroll
        for (int mi = 0; mi < 2; ++mi)
#pragma unroll
            for (int ni = 0; ni < 4; ++ni) {
                acc[mi][ni] = MFMA16(ah[mi], bh[ni], acc[mi][ni], 0, 0, 0);
                acc[mi][ni] = MFMA16(ah[mi], bl[ni], acc[mi][ni], 0, 0, 0);
                acc[mi][ni] = MFMA16(al[mi], bh[ni], acc[mi][ni], 0, 0, 0);
            }
        __syncthreads();
    }

    u16* vH = lds;
    u16* vL = lds + 8704;
    u16* W1sH = lds + 17408;
    u16* W1sL = lds + 19584;
    {
        int cls = tid >> 4, kc = (tid & 15) * 8;
        *(s16x8*)&W1sH[cls * 136 + kc] = *(const s16x8*)&W1Th[(size_t)cls * FCU + co + kc];
        *(s16x8*)&W1sL[cls * 136 + kc] = *(const s16x8*)&W1Tl[(size_t)cls * FCU + co + kc];
    }
#pragma unroll
    for (int mi = 0; mi < 2; ++mi)
#pragma unroll
        for (int ni = 0; ni < 4; ++ni) {
            int unit = wc * 64 + ni * 16 + l15;
            float b0v = fc0b[co + unit];
#pragma unroll
            for (int j = 0; j < 4; ++j) {
                int rl = wr * 32 + mi * 16 + l4 * 4 + j;
                float v = fmaxf(acc[mi][ni][j] + b0v, 0.f);
                u16 h, l;
                split2(v, h, l);
                vH[rl * 136 + unit] = h;
                vL[rl * 136 + unit] = l;
            }
        }
    __syncthreads();

    f32x4 acc2 = {0.f, 0.f, 0.f, 0.f};
#pragma unroll
    for (int ks = 0; ks < 4; ++ks) {
        s16x8 a2h = *(const s16x8*)&vH[(w * 16 + l15) * 136 + ks * 32 + 8 * l4];
        s16x8 a2l = *(const s16x8*)&vL[(w * 16 + l15) * 136 + ks * 32 + 8 * l4];
        s16x8 b2h = *(const s16x8*)&W1sH[l15 * 136 + ks * 32 + 8 * l4];
        s16x8 b2l = *(const s16x8*)&W1sL[l15 * 136 + ks * 32 + 8 * l4];
        acc2 = MFMA16(a2h, b2h, acc2, 0, 0, 0);
        acc2 = MFMA16(a2h, b2l, acc2, 0, 0, 0);
        acc2 = MFMA16(a2l, b2h, acc2, 0, 0, 0);
    }
#pragma unroll
    for (int j = 0; j < 4; ++j) {
        int gr = blockRow + w * 16 + l4 * 4 + j;
        if (gr < M) atomicAdd(&out[(size_t)gr * NCLS + l15], acc2[j]);
    }
}

// ---------------- launch ----------------

extern "C" void kernel_launch(void* const* d_in, const int* in_sizes, int n_in,
                              void* d_out, int out_size, void* d_ws, size_t ws_size,
                              hipStream_t stream)
{
    const float* x     = (const float*)d_in[0];
    const int*   ei    = (const int*)d_in[1];
    const float* gcn0W = (const float*)d_in[2];
    const float* gcn0b = (const float*)d_in[3];
    const float* gcn1W = (const float*)d_in[4];
    const float* gcn1b = (const float*)d_in[5];
    const float* gcn2W = (const float*)d_in[6];
    const float* gcn2b = (const float*)d_in[7];
    const float* w1    = (const float*)d_in[8];
    const float* b1    = (const float*)d_in[9];
    const float* fc0W  = (const float*)d_in[10];
    const float* fc0b  = (const float*)d_in[11];
    const float* fc1W  = (const float*)d_in[12];
    const float* fc1b  = (const float*)d_in[13];
    float* out = (float*)d_out;

    char* ws = (char*)d_ws;
    size_t off = 0;
    auto alloc = [&](size_t bytes) -> void* {
        void* p = ws + off;
        off = (off + bytes + 255) & ~(size_t)255;
        return p;
    };
    int* degS   = (int*)alloc((size_t)2 * NNODES * 4);
    int* cnt    = degS + NNODES;
    int* rowptr = (int*)alloc((size_t)(NNODES + 1) * 4);
    int* cursor = (int*)alloc((size_t)NNODES * 4);
    int* bsum   = (int*)alloc(64 * 4);
    int* csr    = (int*)alloc((size_t)NEDGES * 4);
    float* nrm  = (float*)alloc((size_t)NNODES * 4);
    u16* W0Th = (u16*)alloc((size_t)DIM * HID * 2);  u16* W0Tl = (u16*)alloc((size_t)DIM * HID * 2);
    u16* w1Th = (u16*)alloc((size_t)HID * HID * 2);  u16* w1Tl = (u16*)alloc((size_t)HID * HID * 2);
    u16* W1Th = (u16*)alloc((size_t)HID * HID * 2);  u16* W1Tl = (u16*)alloc((size_t)HID * HID * 2);
    u16* W2Th = (u16*)alloc((size_t)HID * HID * 2);  u16* W2Tl = (u16*)alloc((size_t)HID * HID * 2);
    u16* F0Th = (u16*)alloc((size_t)HID * FCU * 2);  u16* F0Tl = (u16*)alloc((size_t)HID * FCU * 2);
    u16* F1Th = (u16*)alloc((size_t)FCU * NCLS * 2); u16* F1Tl = (u16*)alloc((size_t)FCU * NCLS * 2);
    float* bufG = (float*)alloc((size_t)NNODES * HID * 4);
    u16* R1 = (u16*)alloc((size_t)2 * NNODES * DIM * 2);
    u16* xh = R1, *xl = R1 + (size_t)NNODES * DIM;
    u16* h1H = R1,                            *h1L = R1 + (size_t)NNODES * HID;
    u16* B3H = R1 + (size_t)2 * NNODES * HID, *B3L = R1 + (size_t)3 * NNODES * HID;

    const int M = NNODES;
    hipMemsetAsync(degS, 0, (size_t)2 * NNODES * 4, stream);

    count_kernel<<<(NEDGES + 255) / 256, 256, 0, stream>>>(ei, degS, cnt);
    norm_kernel<<<(NNODES + 255) / 256, 256, 0, stream>>>(degS, nrm);
    const int NB = (NNODES + 1023) / 1024;
    scan_a<<<NB, 1024, 0, stream>>>(cnt, rowptr, bsum);
    scan_b<<<1, 64, 0, stream>>>(bsum, NB);
    scan_c<<<NB, 1024, 0, stream>>>(rowptr, cursor, bsum);
    fill_kernel<<<(NEDGES + 255) / 256, 256, 0, stream>>>(ei, cursor, csr);

    conv_x<<<(NNODES * DIM / 4 + 255) / 256, 256, 0, stream>>>(x, xh, xl);
    conv_wT<<<(DIM * HID + 255) / 256, 256, 0, stream>>>(gcn0W, DIM, HID, W0Th, W0Tl);
    conv_wT<<<(HID * HID + 255) / 256, 256, 0, stream>>>(w1,    HID, HID, w1Th, w1Tl);
    conv_wT<<<(HID * HID + 255) / 256, 256, 0, stream>>>(gcn1W, HID, HID, W1Th, W1Tl);
    conv_wT<<<(HID * HID + 255) / 256, 256, 0, stream>>>(gcn2W, HID, HID, W2Th, W2Tl);
    conv_wT<<<(HID * FCU + 255) / 256, 256, 0, stream>>>(fc0W,  HID, FCU, F0Th, F0Tl);
    conv_wT<<<(FCU * NCLS + 255) / 256, 256, 0, stream>>>(fc1W, FCU, NCLS, F1Th, F1Tl);

    const int GB = (M + 63) / 64;
    const int AB = (NNODES + 3) / 4;
    // gcn0
    gemm_split<DIM, 0><<<GB, 256, 0, stream>>>(xh, xl, W0Th, W0Tl, nullptr, nrm, bufG, nullptr, nullptr, M);
    agg_fast<0><<<AB, 256, 0, stream>>>(bufG, nrm, rowptr, csr, gcn0b, nullptr, nullptr, h1H, h1L);
    // h11 = relu(h1@w1 + b1)
    gemm_split<HID, 1><<<GB, 256, 0, stream>>>(h1H, h1L, w1Th, w1Tl, b1, nullptr, nullptr, B3H, B3L, M);
    // gcn1 (no relu)
    gemm_split<HID, 0><<<GB, 256, 0, stream>>>(B3H, B3L, W1Th, W1Tl, nullptr, nrm, bufG, nullptr, nullptr, M);
    agg_fast<1><<<AB, 256, 0, stream>>>(bufG, nrm, rowptr, csr, gcn1b, nullptr, nullptr, B3H, B3L);
    // gcn2 (relu) + residual
    gemm_split<HID, 0><<<GB, 256, 0, stream>>>(B3H, B3L, W2Th, W2Tl, nullptr, nrm, bufG, nullptr, nullptr, M);
    agg_fast<2><<<AB, 256, 0, stream>>>(bufG, nrm, rowptr, csr, gcn2b, h1H, h1L, B3H, B3L);
    // head
    init_out<<<(NNODES * NCLS + 255) / 256, 256, 0, stream>>>(fc1b, out);
    fc_kernel<<<dim3(GB, FCU / 128), 256, 0, stream>>>(B3H, B3L, F0Th, F0Tl, fc0b, F1Th, F1Tl, out, M);
}

// Round 4
// 631.691 us; speedup vs baseline: 2.1625x; 1.2108x over previous
//
#include <hip/hip_runtime.h>
#include <hip/hip_bf16.h>
#include <cstddef>
#include <cstdint>

#define NNODES 50000
#define NEDGES 1600000
#define DIM 256
#define HID 128
#define FCU 1024
#define NCLS 16

// CSR-build geometry
#define NBKT 256          // dst buckets
#define BW 196            // nodes per bucket (256*196 = 50176 >= NNODES)
#define NBLK_A 64         // phase-A blocks
#define EPB (NEDGES / NBLK_A)   // 25000 edges per A-block (exact)
#define CAPB 8192         // max edges per bucket (mean 6250, +24 sigma)

typedef short s16x8 __attribute__((ext_vector_type(8)));
typedef float f32x4 __attribute__((ext_vector_type(4)));
#define MFMA16 __builtin_amdgcn_mfma_f32_16x16x32_bf16

typedef unsigned short u16;
typedef unsigned int u32;

__device__ inline u16 f2bf(float f) {
    u32 u = __float_as_uint(f);
    return (u16)((u + 0x7FFF + ((u >> 16) & 1)) >> 16);
}
__device__ inline float bf2f(u16 h) { return __uint_as_float(((u32)h) << 16); }
__device__ inline void split2(float v, u16& h, u16& l) {
    h = f2bf(v);
    l = f2bf(v - bf2f(h));
}

// ---------------- graph preprocessing ----------------

__global__ void count_kernel(const int* __restrict__ ei, int* __restrict__ degS) {
    int e = blockIdx.x * blockDim.x + threadIdx.x;
    if (e < NEDGES) atomicAdd(&degS[ei[e]], 1);
}

__global__ void norm_kernel(const int* __restrict__ degS, float* __restrict__ nrm) {
    int i = blockIdx.x * blockDim.x + threadIdx.x;
    if (i < NNODES) nrm[i] = rsqrtf((float)(degS[i] + 1));
}

// Phase A1: per-(bucket, block) histogram
__global__ __launch_bounds__(1024) void histA(const int* __restrict__ ei, int* __restrict__ hist) {
    __shared__ int h[NBKT];
    int blk = blockIdx.x, t = threadIdx.x;
    if (t < NBKT) h[t] = 0;
    __syncthreads();
    int base = blk * EPB;
    for (int e = base + t; e < base + EPB; e += 1024) {
        int dst = ei[NEDGES + e];
        atomicAdd(&h[dst / BW], 1);
    }
    __syncthreads();
    if (t < NBKT) hist[t * NBLK_A + blk] = h[t];
}

// scan over NBKT*NBLK_A = 16384 entries (bucket-major)
__global__ __launch_bounds__(1024) void scanh_a(int* __restrict__ hist, int* __restrict__ bsum) {
    __shared__ int s[1024];
    int b = blockIdx.x, t = threadIdx.x, i = b * 1024 + t;
    int v = hist[i];
    s[t] = v;
    __syncthreads();
    for (int off = 1; off < 1024; off <<= 1) {
        int x = (t >= off) ? s[t - off] : 0;
        __syncthreads();
        s[t] += x;
        __syncthreads();
    }
    hist[i] = s[t] - v;
    if (t == 1023) bsum[b] = s[1023];
}
__global__ void scanh_b(int* __restrict__ bsum) {
    if (threadIdx.x == 0 && blockIdx.x == 0) {
        int a = 0;
        for (int j = 0; j < 16; ++j) { int t = bsum[j]; bsum[j] = a; a += t; }
    }
}
__global__ __launch_bounds__(1024) void scanh_c(int* __restrict__ hist, const int* __restrict__ bsum) {
    int i = blockIdx.x * 1024 + threadIdx.x;
    hist[i] += bsum[blockIdx.x];
}

// Phase A3: stream packed (dst<<16 | src) into per-(block,bucket) regions
__global__ __launch_bounds__(1024) void bucket_fill(const int* __restrict__ ei,
                                                    const int* __restrict__ hist,
                                                    u32* __restrict__ packed) {
    __shared__ int cur[NBKT];
    int blk = blockIdx.x, t = threadIdx.x;
    if (t < NBKT) cur[t] = hist[t * NBLK_A + blk];
    __syncthreads();
    int base = blk * EPB;
    for (int e = base + t; e < base + EPB; e += 1024) {
        int src = ei[e], dst = ei[NEDGES + e];
        int p = atomicAdd(&cur[dst / BW], 1);
        packed[p] = ((u32)dst << 16) | (u32)src;
    }
}

// Phase B: per-bucket counting sort in LDS -> rowptr + u16 csr (coalesced writes)
__global__ __launch_bounds__(256) void bucket_csr(const u32* __restrict__ packed,
                                                  const int* __restrict__ hist,
                                                  int* __restrict__ rowptr, u16* __restrict__ csr) {
    __shared__ u32 st[CAPB];
    __shared__ u16 so[CAPB];
    __shared__ int cnt[256], excl[256];
    int b = blockIdx.x, t = threadIdx.x;
    int ebase = hist[b * NBLK_A];
    int eend  = (b < NBKT - 1) ? hist[(b + 1) * NBLK_A] : NEDGES;
    int nE = eend - ebase;
    if (nE > CAPB) nE = CAPB;
    cnt[t] = 0;
    __syncthreads();
    for (int i = t; i < nE; i += 256) {
        u32 p = packed[ebase + i];
        st[i] = p;
        atomicAdd(&cnt[(int)(p >> 16) - b * BW], 1);
    }
    __syncthreads();
    int v = cnt[t];
    excl[t] = v;
    __syncthreads();
    for (int off = 1; off < 256; off <<= 1) {
        int x = (t >= off) ? excl[t - off] : 0;
        __syncthreads();
        excl[t] += x;
        __syncthreads();
    }
    int ex = excl[t] - v;
    int node = b * BW + t;
    if (t < BW && node < NNODES) rowptr[node] = ebase + ex;
    if (b == NBKT - 1 && t == 0) rowptr[NNODES] = NEDGES;
    cnt[t] = ex;
    __syncthreads();
    for (int i = t; i < nE; i += 256) {
        u32 p = st[i];
        int pos = atomicAdd(&cnt[(int)(p >> 16) - b * BW], 1);
        so[pos] = (u16)(p & 0xFFFF);
    }
    __syncthreads();
    for (int i = t; i < nE; i += 256) csr[ebase + i] = so[i];
}

// ---------------- conversions ----------------

__global__ __launch_bounds__(256) void conv_x(const float* __restrict__ x,
                                              u16* __restrict__ xh, u16* __restrict__ xl) {
    int i = blockIdx.x * blockDim.x + threadIdx.x;
    const float4 v = *reinterpret_cast<const float4*>(x + (size_t)i * 4);
    u16 h0, l0, h1, l1, h2, l2, h3, l3;
    split2(v.x, h0, l0); split2(v.y, h1, l1); split2(v.z, h2, l2); split2(v.w, h3, l3);
    ushort4 hv = make_ushort4(h0, h1, h2, h3), lv = make_ushort4(l0, l1, l2, l3);
    *reinterpret_cast<ushort4*>(xh + (size_t)i * 4) = hv;
    *reinterpret_cast<ushort4*>(xl + (size_t)i * 4) = lv;
}

__global__ __launch_bounds__(256) void conv_wT(const float* __restrict__ W, int K, int N,
                                               u16* __restrict__ outH, u16* __restrict__ outL) {
    int o = blockIdx.x * blockDim.x + threadIdx.x;
    if (o < K * N) {
        int n = o / K, k = o - n * K;
        u16 h, l;
        split2(W[(size_t)k * N + n], h, l);
        outH[o] = h; outL[o] = l;
    }
}

// ---------------- aggregation ----------------
// g rows are PRE-SCALED by nrm[src] in the GEMM epilogue.
// out[i] = nrm[i]*(g[i] + sum_{s in N(i)} g[s]) + bias   (+relu / +residual)

template<int VAR>
__global__ __launch_bounds__(256) void agg_fast(
    const float* __restrict__ g, const float* __restrict__ nrm,
    const int* __restrict__ rowptr, const u16* __restrict__ csr,
    const float* __restrict__ bias,
    const u16* __restrict__ h1H, const u16* __restrict__ h1L,
    u16* __restrict__ outH, u16* __restrict__ outL)
{
    int w = threadIdx.x >> 6, lane = threadIdx.x & 63;
    int i = blockIdx.x * 4 + w;
    if (i >= NNODES) return;
    const float2* gp = reinterpret_cast<const float2*>(g);
    size_t lrow = (size_t)i * 64 + lane;
    float2 acc = gp[lrow];
    int e0 = rowptr[i], e1 = rowptr[i + 1];
    int e = e0;
    for (; e + 8 <= e1; e += 8) {
        int s[8];
#pragma unroll
        for (int q = 0; q < 8; ++q) s[q] = csr[e + q];
        float2 v[8];
#pragma unroll
        for (int q = 0; q < 8; ++q) v[q] = gp[(size_t)s[q] * 64 + lane];
#pragma unroll
        for (int q = 0; q < 8; ++q) { acc.x += v[q].x; acc.y += v[q].y; }
    }
    for (; e < e1; ++e) {
        int s = csr[e];
        float2 v = gp[(size_t)s * 64 + lane];
        acc.x += v.x; acc.y += v.y;
    }
    float ni = nrm[i];
    const float2 b = *reinterpret_cast<const float2*>(bias + lane * 2);
    float v0 = fmaf(ni, acc.x, b.x);
    float v1 = fmaf(ni, acc.y, b.y);
    if (VAR != 1) { v0 = fmaxf(v0, 0.f); v1 = fmaxf(v1, 0.f); }
    if (VAR == 2) {
        ushort2 rh = *reinterpret_cast<const ushort2*>(h1H + (size_t)i * HID + lane * 2);
        ushort2 rl = *reinterpret_cast<const ushort2*>(h1L + (size_t)i * HID + lane * 2);
        v0 += bf2f(rh.x) + bf2f(rl.x);
        v1 += bf2f(rh.y) + bf2f(rl.y);
    }
    u16 h0, l0, h1v, l1v;
    split2(v0, h0, l0);
    split2(v1, h1v, l1v);
    *reinterpret_cast<ushort2*>(outH + (size_t)i * HID + lane * 2) = make_ushort2(h0, h1v);
    *reinterpret_cast<ushort2*>(outL + (size_t)i * HID + lane * 2) = make_ushort2(l0, l1v);
}

// ---------------- split-bf16 MFMA GEMM: [M,K] @ [K,128] ----------------

template<int K, int MODE>
__global__ __launch_bounds__(256) void gemm_split(
    const u16* __restrict__ Ah, const u16* __restrict__ Al,
    const u16* __restrict__ BTh, const u16* __restrict__ BTl,
    const float* __restrict__ pnb, const float* __restrict__ nrmv,
    float* __restrict__ outF, u16* __restrict__ outH, u16* __restrict__ outL, int M)
{
    const int PK = 40;
    __shared__ __align__(16) u16 AsH[64 * PK], AsL[64 * PK];
    __shared__ __align__(16) u16 BsH[128 * PK], BsL[128 * PK];
    int tid = threadIdx.x, lane = tid & 63, w = tid >> 6;
    int wr = w >> 1, wc = w & 1;
    int l15 = lane & 15, l4 = lane >> 4;
    int blockRow = blockIdx.x * 64;
    f32x4 acc[2][4] = {};

    for (int kk = 0; kk < K; kk += 32) {
        {
            int row = tid >> 2, kc = (tid & 3) * 8;
            int gr = blockRow + row; if (gr >= M) gr = M - 1;
            *(s16x8*)&AsH[row * PK + kc] = *(const s16x8*)&Ah[(size_t)gr * K + kk + kc];
            *(s16x8*)&AsL[row * PK + kc] = *(const s16x8*)&Al[(size_t)gr * K + kk + kc];
        }
#pragma unroll
        for (int i2 = 0; i2 < 2; ++i2) {
            int idx = tid + i2 * 256;
            int n = idx >> 2, kc = (idx & 3) * 8;
            *(s16x8*)&BsH[n * PK + kc] = *(const s16x8*)&BTh[(size_t)n * K + kk + kc];
            *(s16x8*)&BsL[n * PK + kc] = *(const s16x8*)&BTl[(size_t)n * K + kk + kc];
        }
        __syncthreads();
        s16x8 ah[2], al[2], bh[4], bl[4];
#pragma unroll
        for (int mi = 0; mi < 2; ++mi) {
            ah[mi] = *(const s16x8*)&AsH[(wr * 32 + mi * 16 + l15) * PK + 8 * l4];
            al[mi] = *(const s16x8*)&AsL[(wr * 32 + mi * 16 + l15) * PK + 8 * l4];
        }
#pragma unroll
        for (int ni = 0; ni < 4; ++ni) {
            bh[ni] = *(const s16x8*)&BsH[(wc * 64 + ni * 16 + l15) * PK + 8 * l4];
            bl[ni] = *(const s16x8*)&BsL[(wc * 64 + ni * 16 + l15) * PK + 8 * l4];
        }
#pragma unroll
        for (int mi = 0; mi < 2; ++mi)
#pragma unroll
            for (int ni = 0; ni < 4; ++ni) {
                acc[mi][ni] = MFMA16(ah[mi], bh[ni], acc[mi][ni], 0, 0, 0);
                acc[mi][ni] = MFMA16(ah[mi], bl[ni], acc[mi][ni], 0, 0, 0);
                acc[mi][ni] = MFMA16(al[mi], bh[ni], acc[mi][ni], 0, 0, 0);
            }
        __syncthreads();
    }
#pragma unroll
    for (int mi = 0; mi < 2; ++mi)
#pragma unroll
        for (int ni = 0; ni < 4; ++ni) {
            int c = wc * 64 + ni * 16 + l15;
#pragma unroll
            for (int j = 0; j < 4; ++j) {
                int r = blockRow + wr * 32 + mi * 16 + l4 * 4 + j;
                if (r < M) {
                    if (MODE == 0) {
                        outF[(size_t)r * 128 + c] = nrmv[r] * acc[mi][ni][j];
                    } else {
                        float v = fmaxf(acc[mi][ni][j] + pnb[(size_t)r * 128 + c], 0.f);
                        u16 h, l;
                        split2(v, h, l);
                        outH[(size_t)r * 128 + c] = h;
                        outL[(size_t)r * 128 + c] = l;
                    }
                }
            }
        }
}

// ---------------- fused fc head ----------------

__global__ void init_out(const float* __restrict__ fc1b, float* __restrict__ out) {
    int i = blockIdx.x * blockDim.x + threadIdx.x;
    if (i < NNODES * NCLS) out[i] = fc1b[i & 15];
}

__global__ __launch_bounds__(256) void fc_kernel(
    const u16* __restrict__ Ah, const u16* __restrict__ Al,
    const u16* __restrict__ BTh, const u16* __restrict__ BTl,
    const float* __restrict__ fc0b,
    const u16* __restrict__ W1Th, const u16* __restrict__ W1Tl,
    float* __restrict__ out, int M)
{
    const int PK = 40;
    __shared__ __align__(16) u16 lds[21760];
    u16* AsH = lds;
    u16* AsL = lds + 2560;
    u16* BsH = lds + 5120;
    u16* BsL = lds + 10240;
    int tid = threadIdx.x, lane = tid & 63, w = tid >> 6;
    int wr = w >> 1, wc = w & 1;
    int l15 = lane & 15, l4 = lane >> 4;
    int blockRow = blockIdx.x * 64;
    int co = blockIdx.y * 128;
    f32x4 acc[2][4] = {};

    for (int kk = 0; kk < HID; kk += 32) {
        {
            int row = tid >> 2, kc = (tid & 3) * 8;
            int gr = blockRow + row; if (gr >= M) gr = M - 1;
            *(s16x8*)&AsH[row * PK + kc] = *(const s16x8*)&Ah[(size_t)gr * HID + kk + kc];
            *(s16x8*)&AsL[row * PK + kc] = *(const s16x8*)&Al[(size_t)gr * HID + kk + kc];
        }
#pragma unroll
        for (int i2 = 0; i2 < 2; ++i2) {
            int idx = tid + i2 * 256;
            int n = idx >> 2, kc = (idx & 3) * 8;
            *(s16x8*)&BsH[n * PK + kc] = *(const s16x8*)&BTh[(size_t)(co + n) * HID + kk + kc];
            *(s16x8*)&BsL[n * PK + kc] = *(const s16x8*)&BTl[(size_t)(co + n) * HID + kk + kc];
        }
        __syncthreads();
        s16x8 ah[2], al[2], bh[4], bl[4];
#pragma unroll
        for (int mi = 0; mi < 2; ++mi) {
            ah[mi] = *(const s16x8*)&AsH[(wr * 32 + mi * 16 + l15) * PK + 8 * l4];
            al[mi] = *(const s16x8*)&AsL[(wr * 32 + mi * 16 + l15) * PK + 8 * l4];
        }
#pragma unroll
        for (int ni = 0; ni < 4; ++ni) {
            bh[ni] = *(const s16x8*)&BsH[(wc * 64 + ni * 16 + l15) * PK + 8 * l4];
            bl[ni] = *(const s16x8*)&BsL[(wc * 64 + ni * 16 + l15) * PK + 8 * l4];
        }
#pragma unroll
        for (int mi = 0; mi < 2; ++mi)
#pragma unroll
            for (int ni = 0; ni < 4; ++ni) {
                acc[mi][ni] = MFMA16(ah[mi], bh[ni], acc[mi][ni], 0, 0, 0);
                acc[mi][ni] = MFMA16(ah[mi], bl[ni], acc[mi][ni], 0, 0, 0);
                acc[mi][ni] = MFMA16(al[mi], bh[ni], acc[mi][ni], 0, 0, 0);
            }
        __syncthreads();
    }

    u16* vH = lds;
    u16* vL = lds + 8704;
    u16* W1sH = lds + 17408;
    u16* W1sL = lds + 19584;
    {
        int cls = tid >> 4, kc = (tid & 15) * 8;
        *(s16x8*)&W1sH[cls * 136 + kc] = *(const s16x8*)&W1Th[(size_t)cls * FCU + co + kc];
        *(s16x8*)&W1sL[cls * 136 + kc] = *(const s16x8*)&W1Tl[(size_t)cls * FCU + co + kc];
    }
#pragma unroll
    for (int mi = 0; mi < 2; ++mi)
#pragma unroll
        for (int ni = 0; ni < 4; ++ni) {
            int unit = wc * 64 + ni * 16 + l15;
            float b0v = fc0b[co + unit];
#pragma unroll
            for (int j = 0; j < 4; ++j) {
                int rl = wr * 32 + mi * 16 + l4 * 4 + j;
                float v = fmaxf(acc[mi][ni][j] + b0v, 0.f);
                u16 h, l;
                split2(v, h, l);
                vH[rl * 136 + unit] = h;
                vL[rl * 136 + unit] = l;
            }
        }
    __syncthreads();

    f32x4 acc2 = {0.f, 0.f, 0.f, 0.f};
#pragma unroll
    for (int ks = 0; ks < 4; ++ks) {
        s16x8 a2h = *(const s16x8*)&vH[(w * 16 + l15) * 136 + ks * 32 + 8 * l4];
        s16x8 a2l = *(const s16x8*)&vL[(w * 16 + l15) * 136 + ks * 32 + 8 * l4];
        s16x8 b2h = *(const s16x8*)&W1sH[l15 * 136 + ks * 32 + 8 * l4];
        s16x8 b2l = *(const s16x8*)&W1sL[l15 * 136 + ks * 32 + 8 * l4];
        acc2 = MFMA16(a2h, b2h, acc2, 0, 0, 0);
        acc2 = MFMA16(a2h, b2l, acc2, 0, 0, 0);
        acc2 = MFMA16(a2l, b2h, acc2, 0, 0, 0);
    }
#pragma unroll
    for (int j = 0; j < 4; ++j) {
        int gr = blockRow + w * 16 + l4 * 4 + j;
        if (gr < M) atomicAdd(&out[(size_t)gr * NCLS + l15], acc2[j]);
    }
}

// ---------------- launch ----------------

extern "C" void kernel_launch(void* const* d_in, const int* in_sizes, int n_in,
                              void* d_out, int out_size, void* d_ws, size_t ws_size,
                              hipStream_t stream)
{
    const float* x     = (const float*)d_in[0];
    const int*   ei    = (const int*)d_in[1];
    const float* gcn0W = (const float*)d_in[2];
    const float* gcn0b = (const float*)d_in[3];
    const float* gcn1W = (const float*)d_in[4];
    const float* gcn1b = (const float*)d_in[5];
    const float* gcn2W = (const float*)d_in[6];
    const float* gcn2b = (const float*)d_in[7];
    const float* w1    = (const float*)d_in[8];
    const float* b1    = (const float*)d_in[9];
    const float* fc0W  = (const float*)d_in[10];
    const float* fc0b  = (const float*)d_in[11];
    const float* fc1W  = (const float*)d_in[12];
    const float* fc1b  = (const float*)d_in[13];
    float* out = (float*)d_out;

    char* ws = (char*)d_ws;
    size_t off = 0;
    auto alloc = [&](size_t bytes) -> void* {
        void* p = ws + off;
        off = (off + bytes + 255) & ~(size_t)255;
        return p;
    };
    int* degS   = (int*)alloc((size_t)NNODES * 4);
    int* rowptr = (int*)alloc((size_t)(NNODES + 1) * 4);
    int* hist   = (int*)alloc((size_t)NBKT * NBLK_A * 4);
    int* bsum   = (int*)alloc(64 * 4);
    u32* packed = (u32*)alloc((size_t)NEDGES * 4);
    u16* csr    = (u16*)alloc((size_t)NEDGES * 2);
    float* nrm  = (float*)alloc((size_t)NNODES * 4);
    u16* W0Th = (u16*)alloc((size_t)DIM * HID * 2);  u16* W0Tl = (u16*)alloc((size_t)DIM * HID * 2);
    u16* w1Th = (u16*)alloc((size_t)HID * HID * 2);  u16* w1Tl = (u16*)alloc((size_t)HID * HID * 2);
    u16* W1Th = (u16*)alloc((size_t)HID * HID * 2);  u16* W1Tl = (u16*)alloc((size_t)HID * HID * 2);
    u16* W2Th = (u16*)alloc((size_t)HID * HID * 2);  u16* W2Tl = (u16*)alloc((size_t)HID * HID * 2);
    u16* F0Th = (u16*)alloc((size_t)HID * FCU * 2);  u16* F0Tl = (u16*)alloc((size_t)HID * FCU * 2);
    u16* F1Th = (u16*)alloc((size_t)FCU * NCLS * 2); u16* F1Tl = (u16*)alloc((size_t)FCU * NCLS * 2);
    float* bufG = (float*)alloc((size_t)NNODES * HID * 4);
    u16* R1 = (u16*)alloc((size_t)2 * NNODES * DIM * 2);
    u16* xh = R1, *xl = R1 + (size_t)NNODES * DIM;
    u16* h1H = R1,                            *h1L = R1 + (size_t)NNODES * HID;
    u16* B3H = R1 + (size_t)2 * NNODES * HID, *B3L = R1 + (size_t)3 * NNODES * HID;

    const int M = NNODES;
    hipMemsetAsync(degS, 0, (size_t)NNODES * 4, stream);

    // graph preprocessing: degree + bucketed counting-sort CSR build
    count_kernel<<<(NEDGES + 255) / 256, 256, 0, stream>>>(ei, degS);
    norm_kernel<<<(NNODES + 255) / 256, 256, 0, stream>>>(degS, nrm);
    histA<<<NBLK_A, 1024, 0, stream>>>(ei, hist);
    scanh_a<<<16, 1024, 0, stream>>>(hist, bsum);
    scanh_b<<<1, 64, 0, stream>>>(bsum);
    scanh_c<<<16, 1024, 0, stream>>>(hist, bsum);
    bucket_fill<<<NBLK_A, 1024, 0, stream>>>(ei, hist, packed);
    bucket_csr<<<NBKT, 256, 0, stream>>>(packed, hist, rowptr, csr);

    // conversions
    conv_x<<<(NNODES * DIM / 4 + 255) / 256, 256, 0, stream>>>(x, xh, xl);
    conv_wT<<<(DIM * HID + 255) / 256, 256, 0, stream>>>(gcn0W, DIM, HID, W0Th, W0Tl);
    conv_wT<<<(HID * HID + 255) / 256, 256, 0, stream>>>(w1,    HID, HID, w1Th, w1Tl);
    conv_wT<<<(HID * HID + 255) / 256, 256, 0, stream>>>(gcn1W, HID, HID, W1Th, W1Tl);
    conv_wT<<<(HID * HID + 255) / 256, 256, 0, stream>>>(gcn2W, HID, HID, W2Th, W2Tl);
    conv_wT<<<(HID * FCU + 255) / 256, 256, 0, stream>>>(fc0W,  HID, FCU, F0Th, F0Tl);
    conv_wT<<<(FCU * NCLS + 255) / 256, 256, 0, stream>>>(fc1W, FCU, NCLS, F1Th, F1Tl);

    const int GB = (M + 63) / 64;
    const int AB = (NNODES + 3) / 4;
    // gcn0
    gemm_split<DIM, 0><<<GB, 256, 0, stream>>>(xh, xl, W0Th, W0Tl, nullptr, nrm, bufG, nullptr, nullptr, M);
    agg_fast<0><<<AB, 256, 0, stream>>>(bufG, nrm, rowptr, csr, gcn0b, nullptr, nullptr, h1H, h1L);
    // h11 = relu(h1@w1 + b1)
    gemm_split<HID, 1><<<GB, 256, 0, stream>>>(h1H, h1L, w1Th, w1Tl, b1, nullptr, nullptr, B3H, B3L, M);
    // gcn1 (no relu)
    gemm_split<HID, 0><<<GB, 256, 0, stream>>>(B3H, B3L, W1Th, W1Tl, nullptr, nrm, bufG, nullptr, nullptr, M);
    agg_fast<1><<<AB, 256, 0, stream>>>(bufG, nrm, rowptr, csr, gcn1b, nullptr, nullptr, B3H, B3L);
    // gcn2 (relu) + residual
    gemm_split<HID, 0><<<GB, 256, 0, stream>>>(B3H, B3L, W2Th, W2Tl, nullptr, nrm, bufG, nullptr, nullptr, M);
    agg_fast<2><<<AB, 256, 0, stream>>>(bufG, nrm, rowptr, csr, gcn2b, h1H, h1L, B3H, B3L);
    // head
    init_out<<<(NNODES * NCLS + 255) / 256, 256, 0, stream>>>(fc1b, out);
    fc_kernel<<<dim3(GB, FCU / 128), 256, 0, stream>>>(B3H, B3L, F0Th, F0Tl, fc0b, F1Th, F1Tl, out, M);
}

// Round 5
// 522.339 us; speedup vs baseline: 2.6153x; 1.2094x over previous
//
#include <hip/hip_runtime.h>
#include <hip/hip_bf16.h>
#include <hip/hip_fp16.h>
#include <cstddef>
#include <cstdint>

#define NNODES 50000
#define NEDGES 1600000
#define DIM 256
#define HID 128
#define FCU 1024
#define NCLS 16

// CSR-build geometry
#define NBKT 256
#define BW 196
#define NBLK_A 64
#define EPB (NEDGES / NBLK_A)
#define CAPB 8192

typedef short s16x8 __attribute__((ext_vector_type(8)));
typedef float f32x4 __attribute__((ext_vector_type(4)));
#define MFMA16 __builtin_amdgcn_mfma_f32_16x16x32_bf16

typedef unsigned short u16;
typedef unsigned int u32;

__device__ inline u16 f2bf(float f) {
    u32 u = __float_as_uint(f);
    return (u16)((u + 0x7FFF + ((u >> 16) & 1)) >> 16);
}
__device__ inline float bf2f(u16 h) { return __uint_as_float(((u32)h) << 16); }
__device__ inline void split2(float v, u16& h, u16& l) {
    h = f2bf(v);
    l = f2bf(v - bf2f(h));
}

// ---------------- graph preprocessing ----------------

__global__ void count_kernel(const int* __restrict__ ei, int* __restrict__ degS) {
    int e = blockIdx.x * blockDim.x + threadIdx.x;
    if (e < NEDGES) atomicAdd(&degS[ei[e]], 1);
}

__global__ void norm_kernel(const int* __restrict__ degS, float* __restrict__ nrm) {
    int i = blockIdx.x * blockDim.x + threadIdx.x;
    if (i < NNODES) nrm[i] = rsqrtf((float)(degS[i] + 1));
}

__global__ __launch_bounds__(1024) void histA(const int* __restrict__ ei, int* __restrict__ hist) {
    __shared__ int h[NBKT];
    int blk = blockIdx.x, t = threadIdx.x;
    if (t < NBKT) h[t] = 0;
    __syncthreads();
    int base = blk * EPB;
    for (int e = base + t; e < base + EPB; e += 1024) {
        int dst = ei[NEDGES + e];
        atomicAdd(&h[dst / BW], 1);
    }
    __syncthreads();
    if (t < NBKT) hist[t * NBLK_A + blk] = h[t];
}

__global__ __launch_bounds__(1024) void scanh_a(int* __restrict__ hist, int* __restrict__ bsum) {
    __shared__ int s[1024];
    int b = blockIdx.x, t = threadIdx.x, i = b * 1024 + t;
    int v = hist[i];
    s[t] = v;
    __syncthreads();
    for (int off = 1; off < 1024; off <<= 1) {
        int x = (t >= off) ? s[t - off] : 0;
        __syncthreads();
        s[t] += x;
        __syncthreads();
    }
    hist[i] = s[t] - v;
    if (t == 1023) bsum[b] = s[1023];
}
__global__ void scanh_b(int* __restrict__ bsum) {
    if (threadIdx.x == 0 && blockIdx.x == 0) {
        int a = 0;
        for (int j = 0; j < 16; ++j) { int t = bsum[j]; bsum[j] = a; a += t; }
    }
}
__global__ __launch_bounds__(1024) void scanh_c(int* __restrict__ hist, const int* __restrict__ bsum) {
    int i = blockIdx.x * 1024 + threadIdx.x;
    hist[i] += bsum[blockIdx.x];
}

__global__ __launch_bounds__(1024) void bucket_fill(const int* __restrict__ ei,
                                                    const int* __restrict__ hist,
                                                    u32* __restrict__ packed) {
    __shared__ int cur[NBKT];
    int blk = blockIdx.x, t = threadIdx.x;
    if (t < NBKT) cur[t] = hist[t * NBLK_A + blk];
    __syncthreads();
    int base = blk * EPB;
    for (int e = base + t; e < base + EPB; e += 1024) {
        int src = ei[e], dst = ei[NEDGES + e];
        int p = atomicAdd(&cur[dst / BW], 1);
        packed[p] = ((u32)dst << 16) | (u32)src;
    }
}

__global__ __launch_bounds__(256) void bucket_csr(const u32* __restrict__ packed,
                                                  const int* __restrict__ hist,
                                                  int* __restrict__ rowptr, u16* __restrict__ csr) {
    __shared__ u32 st[CAPB];
    __shared__ u16 so[CAPB];
    __shared__ int cnt[256], excl[256];
    int b = blockIdx.x, t = threadIdx.x;
    int ebase = hist[b * NBLK_A];
    int eend  = (b < NBKT - 1) ? hist[(b + 1) * NBLK_A] : NEDGES;
    int nE = eend - ebase;
    if (nE > CAPB) nE = CAPB;
    cnt[t] = 0;
    __syncthreads();
    for (int i = t; i < nE; i += 256) {
        u32 p = packed[ebase + i];
        st[i] = p;
        atomicAdd(&cnt[(int)(p >> 16) - b * BW], 1);
    }
    __syncthreads();
    int v = cnt[t];
    excl[t] = v;
    __syncthreads();
    for (int off = 1; off < 256; off <<= 1) {
        int x = (t >= off) ? excl[t - off] : 0;
        __syncthreads();
        excl[t] += x;
        __syncthreads();
    }
    int ex = excl[t] - v;
    int node = b * BW + t;
    if (t < BW && node < NNODES) rowptr[node] = ebase + ex;
    if (b == NBKT - 1 && t == 0) rowptr[NNODES] = NEDGES;
    cnt[t] = ex;
    __syncthreads();
    for (int i = t; i < nE; i += 256) {
        u32 p = st[i];
        int pos = atomicAdd(&cnt[(int)(p >> 16) - b * BW], 1);
        so[pos] = (u16)(p & 0xFFFF);
    }
    __syncthreads();
    for (int i = t; i < nE; i += 256) csr[ebase + i] = so[i];
}

// ---------------- conversions ----------------

__global__ __launch_bounds__(256) void conv_x(const float* __restrict__ x,
                                              u16* __restrict__ xh, u16* __restrict__ xl) {
    int i = blockIdx.x * blockDim.x + threadIdx.x;
    const float4 v = *reinterpret_cast<const float4*>(x + (size_t)i * 4);
    u16 h0, l0, h1, l1, h2, l2, h3, l3;
    split2(v.x, h0, l0); split2(v.y, h1, l1); split2(v.z, h2, l2); split2(v.w, h3, l3);
    ushort4 hv = make_ushort4(h0, h1, h2, h3), lv = make_ushort4(l0, l1, l2, l3);
    *reinterpret_cast<ushort4*>(xh + (size_t)i * 4) = hv;
    *reinterpret_cast<ushort4*>(xl + (size_t)i * 4) = lv;
}

__global__ __launch_bounds__(256) void conv_wT(const float* __restrict__ W, int K, int N,
                                               u16* __restrict__ outH, u16* __restrict__ outL) {
    int o = blockIdx.x * blockDim.x + threadIdx.x;
    if (o < K * N) {
        int n = o / K, k = o - n * K;
        u16 h, l;
        split2(W[(size_t)k * N + n], h, l);
        outH[o] = h; outL[o] = l;
    }
}

// ---------------- aggregation ----------------
// g rows (fp16, PRE-SCALED by nrm[src]).
// out[i] = nrm[i]*(g[i] + sum_{s in N(i)} g[s]) + bias   (+relu / +residual)

template<int VAR>
__global__ __launch_bounds__(256) void agg_fast(
    const __half* __restrict__ g, const float* __restrict__ nrm,
    const int* __restrict__ rowptr, const u16* __restrict__ csr,
    const float* __restrict__ bias,
    const u16* __restrict__ h1H, const u16* __restrict__ h1L,
    u16* __restrict__ outH, u16* __restrict__ outL)
{
    int w = threadIdx.x >> 6, lane = threadIdx.x & 63;
    int i = blockIdx.x * 4 + w;
    if (i >= NNODES) return;
    const __half2* gp = reinterpret_cast<const __half2*>(g);
    size_t lrow = (size_t)i * 64 + lane;
    float2 acc = __half22float2(gp[lrow]);
    int e0 = rowptr[i], e1 = rowptr[i + 1];
    int e = e0;
    for (; e + 8 <= e1; e += 8) {
        int s[8];
#pragma unroll
        for (int q = 0; q < 8; ++q) s[q] = csr[e + q];
        __half2 v[8];
#pragma unroll
        for (int q = 0; q < 8; ++q) v[q] = gp[(size_t)s[q] * 64 + lane];
#pragma unroll
        for (int q = 0; q < 8; ++q) {
            float2 f = __half22float2(v[q]);
            acc.x += f.x; acc.y += f.y;
        }
    }
    for (; e < e1; ++e) {
        int s = csr[e];
        float2 f = __half22float2(gp[(size_t)s * 64 + lane]);
        acc.x += f.x; acc.y += f.y;
    }
    float ni = nrm[i];
    const float2 b = *reinterpret_cast<const float2*>(bias + lane * 2);
    float v0 = fmaf(ni, acc.x, b.x);
    float v1 = fmaf(ni, acc.y, b.y);
    if (VAR != 1) { v0 = fmaxf(v0, 0.f); v1 = fmaxf(v1, 0.f); }
    if (VAR == 2) {
        ushort2 rh = *reinterpret_cast<const ushort2*>(h1H + (size_t)i * HID + lane * 2);
        ushort2 rl = *reinterpret_cast<const ushort2*>(h1L + (size_t)i * HID + lane * 2);
        v0 += bf2f(rh.x) + bf2f(rl.x);
        v1 += bf2f(rh.y) + bf2f(rl.y);
    }
    u16 h0, l0, h1v, l1v;
    split2(v0, h0, l0);
    split2(v1, h1v, l1v);
    *reinterpret_cast<ushort2*>(outH + (size_t)i * HID + lane * 2) = make_ushort2(h0, h1v);
    *reinterpret_cast<ushort2*>(outL + (size_t)i * HID + lane * 2) = make_ushort2(l0, l1v);
}

// ---------------- split-bf16 MFMA GEMM: [M,K] @ [K,128] ----------------
// MODE 0: out fp16 [M,128] scaled by nrm[r] (feeds aggregation).
// MODE 1: per-node bias (b1) + relu, out hi/lo planes.

template<int K, int MODE>
__global__ __launch_bounds__(256) void gemm_split(
    const u16* __restrict__ Ah, const u16* __restrict__ Al,
    const u16* __restrict__ BTh, const u16* __restrict__ BTl,
    const float* __restrict__ pnb, const float* __restrict__ nrmv,
    __half* __restrict__ outG, u16* __restrict__ outH, u16* __restrict__ outL, int M)
{
    const int PK = 40;
    __shared__ __align__(16) u16 AsH[64 * PK], AsL[64 * PK];
    __shared__ __align__(16) u16 BsH[128 * PK], BsL[128 * PK];
    int tid = threadIdx.x, lane = tid & 63, w = tid >> 6;
    int wr = w >> 1, wc = w & 1;
    int l15 = lane & 15, l4 = lane >> 4;
    int blockRow = blockIdx.x * 64;
    f32x4 acc[2][4] = {};

    for (int kk = 0; kk < K; kk += 32) {
        {
            int row = tid >> 2, kc = (tid & 3) * 8;
            int gr = blockRow + row; if (gr >= M) gr = M - 1;
            *(s16x8*)&AsH[row * PK + kc] = *(const s16x8*)&Ah[(size_t)gr * K + kk + kc];
            *(s16x8*)&AsL[row * PK + kc] = *(const s16x8*)&Al[(size_t)gr * K + kk + kc];
        }
#pragma unroll
        for (int i2 = 0; i2 < 2; ++i2) {
            int idx = tid + i2 * 256;
            int n = idx >> 2, kc = (idx & 3) * 8;
            *(s16x8*)&BsH[n * PK + kc] = *(const s16x8*)&BTh[(size_t)n * K + kk + kc];
            *(s16x8*)&BsL[n * PK + kc] = *(const s16x8*)&BTl[(size_t)n * K + kk + kc];
        }
        __syncthreads();
        s16x8 ah[2], al[2], bh[4], bl[4];
#pragma unroll
        for (int mi = 0; mi < 2; ++mi) {
            ah[mi] = *(const s16x8*)&AsH[(wr * 32 + mi * 16 + l15) * PK + 8 * l4];
            al[mi] = *(const s16x8*)&AsL[(wr * 32 + mi * 16 + l15) * PK + 8 * l4];
        }
#pragma unroll
        for (int ni = 0; ni < 4; ++ni) {
            bh[ni] = *(const s16x8*)&BsH[(wc * 64 + ni * 16 + l15) * PK + 8 * l4];
            bl[ni] = *(const s16x8*)&BsL[(wc * 64 + ni * 16 + l15) * PK + 8 * l4];
        }
#pragma unroll
        for (int mi = 0; mi < 2; ++mi)
#pragma unroll
            for (int ni = 0; ni < 4; ++ni) {
                acc[mi][ni] = MFMA16(ah[mi], bh[ni], acc[mi][ni], 0, 0, 0);
                acc[mi][ni] = MFMA16(ah[mi], bl[ni], acc[mi][ni], 0, 0, 0);
                acc[mi][ni] = MFMA16(al[mi], bh[ni], acc[mi][ni], 0, 0, 0);
            }
        __syncthreads();
    }
#pragma unroll
    for (int mi = 0; mi < 2; ++mi)
#pragma unroll
        for (int ni = 0; ni < 4; ++ni) {
            int c = wc * 64 + ni * 16 + l15;
#pragma unroll
            for (int j = 0; j < 4; ++j) {
                int r = blockRow + wr * 32 + mi * 16 + l4 * 4 + j;
                if (r < M) {
                    if (MODE == 0) {
                        outG[(size_t)r * 128 + c] = __float2half(nrmv[r] * acc[mi][ni][j]);
                    } else {
                        float v = fmaxf(acc[mi][ni][j] + pnb[(size_t)r * 128 + c], 0.f);
                        u16 h, l;
                        split2(v, h, l);
                        outH[(size_t)r * 128 + c] = h;
                        outL[(size_t)r * 128 + c] = l;
                    }
                }
            }
        }
}

// ---------------- fused fc head: loops all 8 column chunks, no atomics ----------------

__global__ __launch_bounds__(256) void fc_kernel(
    const u16* __restrict__ Ah, const u16* __restrict__ Al,
    const u16* __restrict__ BTh, const u16* __restrict__ BTl,
    const float* __restrict__ fc0b,
    const u16* __restrict__ W1Th, const u16* __restrict__ W1Tl,
    const float* __restrict__ fc1b,
    float* __restrict__ out, int M)
{
    const int PK = 40;
    __shared__ __align__(16) u16 lds[21760];
    u16* AsH = lds;
    u16* AsL = lds + 2560;
    u16* BsH = lds + 5120;
    u16* BsL = lds + 10240;
    u16* vH = lds;
    u16* vL = lds + 8704;
    u16* W1sH = lds + 17408;
    u16* W1sL = lds + 19584;
    int tid = threadIdx.x, lane = tid & 63, w = tid >> 6;
    int wr = w >> 1, wc = w & 1;
    int l15 = lane & 15, l4 = lane >> 4;
    int blockRow = blockIdx.x * 64;
    f32x4 acc2 = {0.f, 0.f, 0.f, 0.f};

    for (int cc = 0; cc < FCU / 128; ++cc) {
        int co = cc * 128;
        f32x4 acc[2][4] = {};
        for (int kk = 0; kk < HID; kk += 32) {
            {
                int row = tid >> 2, kc = (tid & 3) * 8;
                int gr = blockRow + row; if (gr >= M) gr = M - 1;
                *(s16x8*)&AsH[row * PK + kc] = *(const s16x8*)&Ah[(size_t)gr * HID + kk + kc];
                *(s16x8*)&AsL[row * PK + kc] = *(const s16x8*)&Al[(size_t)gr * HID + kk + kc];
            }
#pragma unroll
            for (int i2 = 0; i2 < 2; ++i2) {
                int idx = tid + i2 * 256;
                int n = idx >> 2, kc = (idx & 3) * 8;
                *(s16x8*)&BsH[n * PK + kc] = *(const s16x8*)&BTh[(size_t)(co + n) * HID + kk + kc];
                *(s16x8*)&BsL[n * PK + kc] = *(const s16x8*)&BTl[(size_t)(co + n) * HID + kk + kc];
            }
            __syncthreads();
            s16x8 ah[2], al[2], bh[4], bl[4];
#pragma unroll
            for (int mi = 0; mi < 2; ++mi) {
                ah[mi] = *(const s16x8*)&AsH[(wr * 32 + mi * 16 + l15) * PK + 8 * l4];
                al[mi] = *(const s16x8*)&AsL[(wr * 32 + mi * 16 + l15) * PK + 8 * l4];
            }
#pragma unroll
            for (int ni = 0; ni < 4; ++ni) {
                bh[ni] = *(const s16x8*)&BsH[(wc * 64 + ni * 16 + l15) * PK + 8 * l4];
                bl[ni] = *(const s16x8*)&BsL[(wc * 64 + ni * 16 + l15) * PK + 8 * l4];
            }
#pragma unroll
            for (int mi = 0; mi < 2; ++mi)
#pragma unroll
                for (int ni = 0; ni < 4; ++ni) {
                    acc[mi][ni] = MFMA16(ah[mi], bh[ni], acc[mi][ni], 0, 0, 0);
                    acc[mi][ni] = MFMA16(ah[mi], bl[ni], acc[mi][ni], 0, 0, 0);
                    acc[mi][ni] = MFMA16(al[mi], bh[ni], acc[mi][ni], 0, 0, 0);
                }
            __syncthreads();
        }

        {
            int cls = tid >> 4, kc = (tid & 15) * 8;
            *(s16x8*)&W1sH[cls * 136 + kc] = *(const s16x8*)&W1Th[(size_t)cls * FCU + co + kc];
            *(s16x8*)&W1sL[cls * 136 + kc] = *(const s16x8*)&W1Tl[(size_t)cls * FCU + co + kc];
        }
#pragma unroll
        for (int mi = 0; mi < 2; ++mi)
#pragma unroll
            for (int ni = 0; ni < 4; ++ni) {
                int unit = wc * 64 + ni * 16 + l15;
                float b0v = fc0b[co + unit];
#pragma unroll
                for (int j = 0; j < 4; ++j) {
                    int rl = wr * 32 + mi * 16 + l4 * 4 + j;
                    float v = fmaxf(acc[mi][ni][j] + b0v, 0.f);
                    u16 h, l;
                    split2(v, h, l);
                    vH[rl * 136 + unit] = h;
                    vL[rl * 136 + unit] = l;
                }
            }
        __syncthreads();

#pragma unroll
        for (int ks = 0; ks < 4; ++ks) {
            s16x8 a2h = *(const s16x8*)&vH[(w * 16 + l15) * 136 + ks * 32 + 8 * l4];
            s16x8 a2l = *(const s16x8*)&vL[(w * 16 + l15) * 136 + ks * 32 + 8 * l4];
            s16x8 b2h = *(const s16x8*)&W1sH[l15 * 136 + ks * 32 + 8 * l4];
            s16x8 b2l = *(const s16x8*)&W1sL[l15 * 136 + ks * 32 + 8 * l4];
            acc2 = MFMA16(a2h, b2h, acc2, 0, 0, 0);
            acc2 = MFMA16(a2h, b2l, acc2, 0, 0, 0);
            acc2 = MFMA16(a2l, b2h, acc2, 0, 0, 0);
        }
        __syncthreads();   // protect LDS before next chunk's staging
    }

#pragma unroll
    for (int j = 0; j < 4; ++j) {
        int gr = blockRow + w * 16 + l4 * 4 + j;
        if (gr < M) out[(size_t)gr * NCLS + l15] = acc2[j] + fc1b[l15];
    }
}

// ---------------- launch ----------------

extern "C" void kernel_launch(void* const* d_in, const int* in_sizes, int n_in,
                              void* d_out, int out_size, void* d_ws, size_t ws_size,
                              hipStream_t stream)
{
    const float* x     = (const float*)d_in[0];
    const int*   ei    = (const int*)d_in[1];
    const float* gcn0W = (const float*)d_in[2];
    const float* gcn0b = (const float*)d_in[3];
    const float* gcn1W = (const float*)d_in[4];
    const float* gcn1b = (const float*)d_in[5];
    const float* gcn2W = (const float*)d_in[6];
    const float* gcn2b = (const float*)d_in[7];
    const float* w1    = (const float*)d_in[8];
    const float* b1    = (const float*)d_in[9];
    const float* fc0W  = (const float*)d_in[10];
    const float* fc0b  = (const float*)d_in[11];
    const float* fc1W  = (const float*)d_in[12];
    const float* fc1b  = (const float*)d_in[13];
    float* out = (float*)d_out;

    char* ws = (char*)d_ws;
    size_t off = 0;
    auto alloc = [&](size_t bytes) -> void* {
        void* p = ws + off;
        off = (off + bytes + 255) & ~(size_t)255;
        return p;
    };
    int* degS   = (int*)alloc((size_t)NNODES * 4);
    int* rowptr = (int*)alloc((size_t)(NNODES + 1) * 4);
    int* hist   = (int*)alloc((size_t)NBKT * NBLK_A * 4);
    int* bsum   = (int*)alloc(64 * 4);
    u32* packed = (u32*)alloc((size_t)NEDGES * 4);
    u16* csr    = (u16*)alloc((size_t)NEDGES * 2);
    float* nrm  = (float*)alloc((size_t)NNODES * 4);
    u16* W0Th = (u16*)alloc((size_t)DIM * HID * 2);  u16* W0Tl = (u16*)alloc((size_t)DIM * HID * 2);
    u16* w1Th = (u16*)alloc((size_t)HID * HID * 2);  u16* w1Tl = (u16*)alloc((size_t)HID * HID * 2);
    u16* W1Th = (u16*)alloc((size_t)HID * HID * 2);  u16* W1Tl = (u16*)alloc((size_t)HID * HID * 2);
    u16* W2Th = (u16*)alloc((size_t)HID * HID * 2);  u16* W2Tl = (u16*)alloc((size_t)HID * HID * 2);
    u16* F0Th = (u16*)alloc((size_t)HID * FCU * 2);  u16* F0Tl = (u16*)alloc((size_t)HID * FCU * 2);
    u16* F1Th = (u16*)alloc((size_t)FCU * NCLS * 2); u16* F1Tl = (u16*)alloc((size_t)FCU * NCLS * 2);
    __half* bufG = (__half*)alloc((size_t)NNODES * HID * 2);
    u16* R1 = (u16*)alloc((size_t)2 * NNODES * DIM * 2);
    u16* xh = R1, *xl = R1 + (size_t)NNODES * DIM;
    u16* h1H = R1,                            *h1L = R1 + (size_t)NNODES * HID;
    u16* B3H = R1 + (size_t)2 * NNODES * HID, *B3L = R1 + (size_t)3 * NNODES * HID;

    const int M = NNODES;
    hipMemsetAsync(degS, 0, (size_t)NNODES * 4, stream);

    count_kernel<<<(NEDGES + 255) / 256, 256, 0, stream>>>(ei, degS);
    norm_kernel<<<(NNODES + 255) / 256, 256, 0, stream>>>(degS, nrm);
    histA<<<NBLK_A, 1024, 0, stream>>>(ei, hist);
    scanh_a<<<16, 1024, 0, stream>>>(hist, bsum);
    scanh_b<<<1, 64, 0, stream>>>(bsum);
    scanh_c<<<16, 1024, 0, stream>>>(hist, bsum);
    bucket_fill<<<NBLK_A, 1024, 0, stream>>>(ei, hist, packed);
    bucket_csr<<<NBKT, 256, 0, stream>>>(packed, hist, rowptr, csr);

    conv_x<<<(NNODES * DIM / 4 + 255) / 256, 256, 0, stream>>>(x, xh, xl);
    conv_wT<<<(DIM * HID + 255) / 256, 256, 0, stream>>>(gcn0W, DIM, HID, W0Th, W0Tl);
    conv_wT<<<(HID * HID + 255) / 256, 256, 0, stream>>>(w1,    HID, HID, w1Th, w1Tl);
    conv_wT<<<(HID * HID + 255) / 256, 256, 0, stream>>>(gcn1W, HID, HID, W1Th, W1Tl);
    conv_wT<<<(HID * HID + 255) / 256, 256, 0, stream>>>(gcn2W, HID, HID, W2Th, W2Tl);
    conv_wT<<<(HID * FCU + 255) / 256, 256, 0, stream>>>(fc0W,  HID, FCU, F0Th, F0Tl);
    conv_wT<<<(FCU * NCLS + 255) / 256, 256, 0, stream>>>(fc1W, FCU, NCLS, F1Th, F1Tl);

    const int GB = (M + 63) / 64;
    const int AB = (NNODES + 3) / 4;
    // gcn0
    gemm_split<DIM, 0><<<GB, 256, 0, stream>>>(xh, xl, W0Th, W0Tl, nullptr, nrm, bufG, nullptr, nullptr, M);
    agg_fast<0><<<AB, 256, 0, stream>>>(bufG, nrm, rowptr, csr, gcn0b, nullptr, nullptr, h1H, h1L);
    // h11 = relu(h1@w1 + b1)
    gemm_split<HID, 1><<<GB, 256, 0, stream>>>(h1H, h1L, w1Th, w1Tl, b1, nullptr, nullptr, B3H, B3L, M);
    // gcn1 (no relu)
    gemm_split<HID, 0><<<GB, 256, 0, stream>>>(B3H, B3L, W1Th, W1Tl, nullptr, nrm, bufG, nullptr, nullptr, M);
    agg_fast<1><<<AB, 256, 0, stream>>>(bufG, nrm, rowptr, csr, gcn1b, nullptr, nullptr, B3H, B3L);
    // gcn2 (relu) + residual
    gemm_split<HID, 0><<<GB, 256, 0, stream>>>(B3H, B3L, W2Th, W2Tl, nullptr, nrm, bufG, nullptr, nullptr, M);
    agg_fast<2><<<AB, 256, 0, stream>>>(bufG, nrm, rowptr, csr, gcn2b, h1H, h1L, B3H, B3L);
    // head
    fc_kernel<<<GB, 256, 0, stream>>>(B3H, B3L, F0Th, F0Tl, fc0b, F1Th, F1Tl, fc1b, out, M);
}